// Round 1
// baseline (1183.892 us; speedup 1.0000x reference)
//
#include <hip/hip_runtime.h>
#include <math.h>

#define B 2
#define L 1024
#define X 4
#define E 128
#define Y 4
#define SCALE 0.08838834764831845f  // 1/sqrt(128)

// ---------------- K0: series_out is identically 0.25 (mean over the softmax axis) ----
__global__ __launch_bounds__(256) void k0_fill(float4* __restrict__ p, int n4) {
  int i = blockIdx.x * 256 + threadIdx.x;
  if (i < n4) p[i] = make_float4(0.25f, 0.25f, 0.25f, 0.25f);
}

// ---------------- K1: scores[b,x,l,s] = scale * <q[b,l,x,:], key[b,s,x,:]> ----------
__global__ __launch_bounds__(256) void k1_scores(const float* __restrict__ q,
                                                 const float* __restrict__ k,
                                                 float* __restrict__ sb) {
  __shared__ float Qt[16][132];
  __shared__ float Kt[64][132];
  const int t = threadIdx.x;
  const int blk = blockIdx.x;
  const int lt = blk & 63;          // L/16 tiles
  const int bx = blk >> 6;          // b*X + x
  const int b = bx >> 2, x = bx & 3;
  const int l0 = lt * 16;
  for (int i = 0; i < 2; ++i) {
    int f = t + i * 256;
    int r = f >> 5, c4 = f & 31;
    float4 v = *(const float4*)(q + ((size_t)((b * L + l0 + r) * X + x)) * E + c4 * 4);
    *(float4*)&Qt[r][c4 * 4] = v;
  }
  const int l = t >> 4;
  const int kk = t & 15;            // m = kk + 16j (interleaved: avoids 16-stride bank clash)
  for (int sc = 0; sc < 16; ++sc) {
    __syncthreads();
    for (int i = 0; i < 8; ++i) {
      int f = t + i * 256;
      int r = f >> 5, c4 = f & 31;
      float4 v = *(const float4*)(k + ((size_t)((b * L + sc * 64 + r) * X + x)) * E + c4 * 4);
      *(float4*)&Kt[r][c4 * 4] = v;
    }
    __syncthreads();
    float d0 = 0.f, d1 = 0.f, d2 = 0.f, d3 = 0.f;
#pragma unroll
    for (int e4 = 0; e4 < 32; ++e4) {
      float4 qv = *(float4*)&Qt[l][e4 * 4];
      float4 k0 = *(float4*)&Kt[kk + 0][e4 * 4];
      float4 k1 = *(float4*)&Kt[kk + 16][e4 * 4];
      float4 k2 = *(float4*)&Kt[kk + 32][e4 * 4];
      float4 k3 = *(float4*)&Kt[kk + 48][e4 * 4];
      d0 += qv.x * k0.x + qv.y * k0.y + qv.z * k0.z + qv.w * k0.w;
      d1 += qv.x * k1.x + qv.y * k1.y + qv.z * k1.z + qv.w * k1.w;
      d2 += qv.x * k2.x + qv.y * k2.y + qv.z * k2.z + qv.w * k2.w;
      d3 += qv.x * k3.x + qv.y * k3.y + qv.z * k3.z + qv.w * k3.w;
    }
    float* o = sb + ((size_t)(bx * L + l0 + l)) * L + sc * 64 + kk;
    o[0] = d0 * SCALE; o[16] = d1 * SCALE; o[32] = d2 * SCALE; o[48] = d3 * SCALE;
  }
}

// ---------------- K2: row softmax over s (in place) ---------------------------------
__global__ __launch_bounds__(256) void k2_softmax(float* __restrict__ sb) {
  __shared__ float red[4];
  const int t = threadIdx.x;
  float* p = sb + (size_t)blockIdx.x * L;
  float4 v = ((float4*)p)[t];
  float mx = fmaxf(fmaxf(v.x, v.y), fmaxf(v.z, v.w));
#pragma unroll
  for (int o = 32; o > 0; o >>= 1) mx = fmaxf(mx, __shfl_down(mx, o, 64));
  if ((t & 63) == 0) red[t >> 6] = mx;
  __syncthreads();
  mx = fmaxf(fmaxf(red[0], red[1]), fmaxf(red[2], red[3]));
  __syncthreads();
  v.x = expf(v.x - mx); v.y = expf(v.y - mx);
  v.z = expf(v.z - mx); v.w = expf(v.w - mx);
  float s = v.x + v.y + v.z + v.w;
#pragma unroll
  for (int o = 32; o > 0; o >>= 1) s += __shfl_down(s, o, 64);
  if ((t & 63) == 0) red[t >> 6] = s;
  __syncthreads();
  s = red[0] + red[1] + red[2] + red[3];
  float inv = 1.0f / s;
  v.x *= inv; v.y *= inv; v.z *= inv; v.w *= inv;
  ((float4*)p)[t] = v;
}

// ---------------- K3: Retr[bxy,l,e] = sum_s Search[b,x,l,s] * value[b,s,y,e] --------
__global__ __launch_bounds__(256) void k3_retr(const float* __restrict__ sb,
                                               const float* __restrict__ value,
                                               float* __restrict__ rb) {
  __shared__ float Pt[32][36];
  __shared__ float Vt[32][132];
  const int t = threadIdx.x;
  const int blk = blockIdx.x;
  const int lt = blk & 31;
  const int bxy = blk >> 5;
  const int b = bxy >> 4;
  const int y = bxy & 3;
  const int l0 = lt * 32;
  const int srow = (bxy >> 2) * L;  // (b*X+x)*L
  const int l = t >> 3;
  const int e0 = (t & 7) << 4;
  float acc[16];
#pragma unroll
  for (int i = 0; i < 16; ++i) acc[i] = 0.f;
  for (int scn = 0; scn < 32; ++scn) {
    __syncthreads();
    {
      int r = t >> 3, c4 = t & 7;
      float4 pv = *(const float4*)(sb + ((size_t)(srow + l0 + r)) * L + scn * 32 + c4 * 4);
      *(float4*)&Pt[r][c4 * 4] = pv;
    }
#pragma unroll
    for (int i = 0; i < 4; ++i) {
      int f = t + i * 256;
      int r = f >> 5, c4 = f & 31;
      float4 vv = *(const float4*)(value + ((size_t)((b * L + scn * 32 + r) * Y + y)) * E + c4 * 4);
      *(float4*)&Vt[r][c4 * 4] = vv;
    }
    __syncthreads();
#pragma unroll 8
    for (int s = 0; s < 32; ++s) {
      float pw = Pt[l][s];
      float4 v0 = *(float4*)&Vt[s][e0 + 0];
      float4 v1 = *(float4*)&Vt[s][e0 + 4];
      float4 v2 = *(float4*)&Vt[s][e0 + 8];
      float4 v3 = *(float4*)&Vt[s][e0 + 12];
      acc[0] += pw * v0.x; acc[1] += pw * v0.y; acc[2] += pw * v0.z; acc[3] += pw * v0.w;
      acc[4] += pw * v1.x; acc[5] += pw * v1.y; acc[6] += pw * v1.z; acc[7] += pw * v1.w;
      acc[8] += pw * v2.x; acc[9] += pw * v2.y; acc[10] += pw * v2.z; acc[11] += pw * v2.w;
      acc[12] += pw * v3.x; acc[13] += pw * v3.y; acc[14] += pw * v3.z; acc[15] += pw * v3.w;
    }
  }
  float* o = rb + ((size_t)(bxy * L + l0 + l)) * E + e0;
  *(float4*)(o + 0) = make_float4(acc[0], acc[1], acc[2], acc[3]);
  *(float4*)(o + 4) = make_float4(acc[4], acc[5], acc[6], acc[7]);
  *(float4*)(o + 8) = make_float4(acc[8], acc[9], acc[10], acc[11]);
  *(float4*)(o + 12) = make_float4(acc[12], acc[13], acc[14], acc[15]);
}

// ---------------- K4: Kp[bxy,m,f] = sum_e Retr[bxy,m,e] * Wk[f,e] + bk[f] -----------
__global__ __launch_bounds__(256) void k4_kp(const float* __restrict__ rb,
                                             const float* __restrict__ Wk,
                                             const float* __restrict__ bk,
                                             float* __restrict__ kp) {
  __shared__ float Rt[32][132];
  __shared__ float Wt[128][36];   // Wk^T tile: [e][f_sub]
  const int t = threadIdx.x;
  const int blk = blockIdx.x;
  const int lt = blk & 31;
  const int bxy = blk >> 5;
  const int l0 = lt * 32;
#pragma unroll
  for (int i = 0; i < 4; ++i) {
    int f = t + i * 256;
    int r = f >> 5, c4 = f & 31;
    *(float4*)&Rt[r][c4 * 4] = *(const float4*)(rb + ((size_t)(bxy * L + l0 + r)) * E + c4 * 4);
  }
  const int m = t >> 3;
  const int fs = (t & 7) << 2;
  for (int ft = 0; ft < 4; ++ft) {
    __syncthreads();
#pragma unroll
    for (int i = 0; i < 4; ++i) {
      int f = t + i * 256;
      int fj = f >> 5, c4 = f & 31;
      float4 wv = *(const float4*)(Wk + (ft * 32 + fj) * E + c4 * 4);
      Wt[c4 * 4 + 0][fj] = wv.x;
      Wt[c4 * 4 + 1][fj] = wv.y;
      Wt[c4 * 4 + 2][fj] = wv.z;
      Wt[c4 * 4 + 3][fj] = wv.w;
    }
    __syncthreads();
    float a0 = 0.f, a1 = 0.f, a2 = 0.f, a3 = 0.f;
#pragma unroll 16
    for (int e = 0; e < 128; ++e) {
      float rv = Rt[m][e];
      float4 wv = *(float4*)&Wt[e][fs];
      a0 += rv * wv.x; a1 += rv * wv.y; a2 += rv * wv.z; a3 += rv * wv.w;
    }
    int fb = ft * 32 + fs;
    float4 o = make_float4(a0 + bk[fb], a1 + bk[fb + 1], a2 + bk[fb + 2], a3 + bk[fb + 3]);
    *(float4*)(kp + ((size_t)(bxy * L + l0 + m)) * E + fb) = o;
  }
}

// ---------------- K5: fused stage 2 -------------------------------------------------
// scores2 -> softmax over y (pointwise in (l,m)) -> accumulate V += P_y * R_y over m,y
__global__ __launch_bounds__(256) void k5_stage2(const float* __restrict__ qp,
                                                 const float* __restrict__ kp,
                                                 const float* __restrict__ rb,
                                                 float* __restrict__ vflat) {
  __shared__ float Qt[32][132];
  __shared__ float Tt[32][132];
  __shared__ float Sc[32][32][4];
  const int t = threadIdx.x;
  const int blk = blockIdx.x;
  const int lt = blk & 31;
  const int bx = (blk >> 5) & 7;
  const int part = blk >> 8;      // split m range across 2 blocks for occupancy
  const int b = bx >> 2, x = bx & 3;
  const int l0 = lt * 32;
#pragma unroll
  for (int i = 0; i < 4; ++i) {
    int f = t + i * 256;
    int r = f >> 5, c4 = f & 31;
    *(float4*)&Qt[r][c4 * 4] =
        *(const float4*)(qp + ((size_t)((b * L + l0 + r) * X + x)) * E + c4 * 4);
  }
  const int l8 = t >> 3;
  const int k7 = t & 7;           // m = k7 + 8j (interleaved lanes: conflict-free LDS)
  const int e0 = (t & 7) << 4;
  float acc[16];
#pragma unroll
  for (int i = 0; i < 16; ++i) acc[i] = 0.f;
  const size_t base = ((size_t)bx) * Y * L * E;
  for (int mc = part * 16; mc < part * 16 + 16; ++mc) {
    for (int y = 0; y <= x; ++y) {
      __syncthreads();
#pragma unroll
      for (int i = 0; i < 4; ++i) {
        int f = t + i * 256;
        int r = f >> 5, c4 = f & 31;
        *(float4*)&Tt[r][c4 * 4] =
            *(const float4*)(kp + base + ((size_t)(y * L + mc * 32 + r)) * E + c4 * 4);
      }
      __syncthreads();
      float d0 = 0.f, d1 = 0.f, d2 = 0.f, d3 = 0.f;
#pragma unroll
      for (int e4 = 0; e4 < 32; ++e4) {
        float4 qv = *(float4*)&Qt[l8][e4 * 4];
        float4 k0 = *(float4*)&Tt[k7 + 0][e4 * 4];
        float4 k1 = *(float4*)&Tt[k7 + 8][e4 * 4];
        float4 k2 = *(float4*)&Tt[k7 + 16][e4 * 4];
        float4 k3 = *(float4*)&Tt[k7 + 24][e4 * 4];
        d0 += qv.x * k0.x + qv.y * k0.y + qv.z * k0.z + qv.w * k0.w;
        d1 += qv.x * k1.x + qv.y * k1.y + qv.z * k1.z + qv.w * k1.w;
        d2 += qv.x * k2.x + qv.y * k2.y + qv.z * k2.z + qv.w * k2.w;
        d3 += qv.x * k3.x + qv.y * k3.y + qv.z * k3.z + qv.w * k3.w;
      }
      Sc[l8][k7 + 0][y] = d0;
      Sc[l8][k7 + 8][y] = d1;
      Sc[l8][k7 + 16][y] = d2;
      Sc[l8][k7 + 24][y] = d3;
    }
    __syncthreads();
#pragma unroll
    for (int i = 0; i < 4; ++i) {
      int pidx = t + i * 256;
      int ll = pidx >> 5, mm = pidx & 31;
      float z[4]; float mxv = -3.4e38f;
      for (int y = 0; y <= x; ++y) { z[y] = Sc[ll][mm][y] * SCALE; mxv = fmaxf(mxv, z[y]); }
      float ev[4]; float sum = 0.f;
      for (int y = 0; y <= x; ++y) { ev[y] = expf(z[y] - mxv); sum += ev[y]; }
      float inv = 1.0f / sum;
      for (int y = 0; y < 4; ++y) Sc[ll][mm][y] = (y <= x) ? ev[y] * inv : 0.f;
    }
    for (int y = 0; y <= x; ++y) {
      __syncthreads();
#pragma unroll
      for (int i = 0; i < 4; ++i) {
        int f = t + i * 256;
        int r = f >> 5, c4 = f & 31;
        *(float4*)&Tt[r][c4 * 4] =
            *(const float4*)(rb + base + ((size_t)(y * L + mc * 32 + r)) * E + c4 * 4);
      }
      __syncthreads();
#pragma unroll 8
      for (int mm = 0; mm < 32; ++mm) {
        float pw = Sc[l8][mm][y];
        float4 v0 = *(float4*)&Tt[mm][e0 + 0];
        float4 v1 = *(float4*)&Tt[mm][e0 + 4];
        float4 v2 = *(float4*)&Tt[mm][e0 + 8];
        float4 v3 = *(float4*)&Tt[mm][e0 + 12];
        acc[0] += pw * v0.x; acc[1] += pw * v0.y; acc[2] += pw * v0.z; acc[3] += pw * v0.w;
        acc[4] += pw * v1.x; acc[5] += pw * v1.y; acc[6] += pw * v1.z; acc[7] += pw * v1.w;
        acc[8] += pw * v2.x; acc[9] += pw * v2.y; acc[10] += pw * v2.z; acc[11] += pw * v2.w;
        acc[12] += pw * v3.x; acc[13] += pw * v3.y; acc[14] += pw * v3.z; acc[15] += pw * v3.w;
      }
    }
  }
  // V[b,l,e,x] scattered to flat (e*4+x), per-part partial buffer
  float* vf = vflat + (size_t)part * (B * L * 512) + ((size_t)(b * L + l0 + l8)) * 512 + x;
#pragma unroll
  for (int i = 0; i < 16; ++i) vf[(e0 + i) * 4] = acc[i];
}

// ---------------- K6: V_out[b,l,s,f] = sum_e Vflat[b,l,s*128+e] * Wv[f,e] + bv[f] ---
__global__ __launch_bounds__(256) void k6_vout(const float* __restrict__ v0,
                                               const float* __restrict__ v1,
                                               const float* __restrict__ Wv,
                                               const float* __restrict__ bv,
                                               float* __restrict__ vout) {
  __shared__ float row[512];
  const int t = threadIdx.x;
  const size_t base = (size_t)blockIdx.x * 512;
  float2 a = ((const float2*)(v0 + base))[t];
  float2 c = ((const float2*)(v1 + base))[t];
  ((float2*)row)[t] = make_float2(a.x + c.x, a.y + c.y);
  __syncthreads();
#pragma unroll
  for (int i = 0; i < 2; ++i) {
    int o = t + i * 256;
    int s = o >> 7, f = o & 127;
    const float4* wr = (const float4*)(Wv + f * E);
    const float4* vr = (const float4*)(row + s * 128);
    float acc = 0.f;
#pragma unroll 8
    for (int e4 = 0; e4 < 32; ++e4) {
      float4 w = wr[e4], vv = vr[e4];
      acc += w.x * vv.x + w.y * vv.y + w.z * vv.z + w.w * vv.w;
    }
    vout[base + o] = acc + bv[f];
  }
}

// ---------------- K7: Gaussian prior + sig output (f64 sigma chain for accuracy) ----
__global__ __launch_bounds__(256) void k7_prior(const float* __restrict__ sigma,
                                                float* __restrict__ prior,
                                                float* __restrict__ sigout) {
  const int row = blockIdx.x;            // (b*X+x)*L + i
  const int bx = row >> 10;
  const int i = row & 1023;
  const int b = bx >> 2, x = bx & 3;
  const double sv = (double)sigma[((size_t)(b * L + i)) * X + x];
  const double sg = 1.0 / (1.0 + exp(-5.0 * sv)) + 1e-5;
  const double s3 = exp(sg * 1.0986122886681098) - 1.0;   // 3^sg - 1
  const float coef = (float)(1.0 / (2.5066282746310002 * s3));
  const float inv2s2 = (float)(0.5 / (s3 * s3));
  const int t = threadIdx.x;
  const float di = (float)i;
  const int j0 = t * 4;
  float4 o; float d;
  d = di - (float)(j0 + 0); o.x = coef * expf(-d * d * inv2s2);
  d = di - (float)(j0 + 1); o.y = coef * expf(-d * d * inv2s2);
  d = di - (float)(j0 + 2); o.z = coef * expf(-d * d * inv2s2);
  d = di - (float)(j0 + 3); o.w = coef * expf(-d * d * inv2s2);
  *(float4*)(prior + (size_t)row * 1024 + j0) = o;
  if (t == 0) sigout[row] = (float)s3;
}

extern "C" void kernel_launch(void* const* d_in, const int* in_sizes, int n_in,
                              void* d_out, int out_size, void* d_ws, size_t ws_size,
                              hipStream_t stream) {
  const float* q     = (const float*)d_in[1];
  const float* key   = (const float*)d_in[2];
  const float* value = (const float*)d_in[3];
  const float* sigma = (const float*)d_in[4];
  const float* qp    = (const float*)d_in[8];
  const float* Wk    = (const float*)d_in[9];
  const float* bk    = (const float*)d_in[10];
  const float* Wv    = (const float*)d_in[11];
  const float* bv    = (const float*)d_in[12];

  float* out    = (float*)d_out;
  float* Vout   = out;                  // [B,L,4,128]
  float* sout   = out + 1048576;        // [B,X,L,L]
  float* prior  = out + 9437184;        // [B,X,L,L]
  float* sigout = out + 17825792;       // [B,X,L,1]

  float* ws    = (float*)d_ws;
  float* sb    = ws;                    // Search scores: 8,388,608 floats
  float* rb    = ws + 8388608;          // Retrieval:     4,194,304 floats
  float* kp    = ws;                    // key_plus: reuses sb region (sb consumed by k3)
  float* vflat = ws + 4194304;          // 2 partial V buffers: 2 x 1,048,576 floats

  hipLaunchKernelGGL(k0_fill,    dim3(8192), dim3(256), 0, stream, (float4*)sout, 2097152);
  hipLaunchKernelGGL(k1_scores,  dim3(512),  dim3(256), 0, stream, q, key, sb);
  hipLaunchKernelGGL(k2_softmax, dim3(8192), dim3(256), 0, stream, sb);
  hipLaunchKernelGGL(k3_retr,    dim3(1024), dim3(256), 0, stream, sb, value, rb);
  hipLaunchKernelGGL(k4_kp,      dim3(1024), dim3(256), 0, stream, rb, Wk, bk, kp);
  hipLaunchKernelGGL(k5_stage2,  dim3(512),  dim3(256), 0, stream, qp, kp, rb, vflat);
  hipLaunchKernelGGL(k6_vout,    dim3(2048), dim3(256), 0, stream, vflat, vflat + 1048576, Wv, bv, Vout);
  hipLaunchKernelGGL(k7_prior,   dim3(8192), dim3(256), 0, stream, sigma, prior, sigout);
}

// Round 2
// 689.016 us; speedup vs baseline: 1.7182x; 1.7182x over previous
//
#include <hip/hip_runtime.h>
#include <math.h>

#define B 2
#define L 1024
#define X 4
#define E 128
#define Y 4
#define SCALE 0.08838834764831845f  // 1/sqrt(128)

typedef unsigned short u16;
typedef __attribute__((ext_vector_type(8))) short bf16frag;   // 8 bf16 (4 VGPRs)
typedef __attribute__((ext_vector_type(4))) float floatx4;    // 4 fp32 acc

// round-to-nearest-even f32 -> bf16
static __device__ __forceinline__ u16 bfr(float f) {
  union { float f; unsigned u; } c; c.f = f;
  unsigned r = (c.u + 0x7fffu + ((c.u >> 16) & 1u)) >> 16;
  return (u16)r;
}

// ---------------- K0: series_out is identically 0.25 (mean over the softmax axis) ----
__global__ __launch_bounds__(256) void k0_fill(float4* __restrict__ p, int n4) {
  int i = blockIdx.x * 256 + threadIdx.x;
  if (i < n4) p[i] = make_float4(0.25f, 0.25f, 0.25f, 0.25f);
}

// ---------------- K1: scores[b,x,l,s] = scale * <q[b,l,x,:], key[b,s,x,:]> ----------
__global__ __launch_bounds__(256) void k1_scores(const float* __restrict__ q,
                                                 const float* __restrict__ k,
                                                 float* __restrict__ sb) {
  __shared__ float Qt[16][132];
  __shared__ float Kt[64][132];
  const int t = threadIdx.x;
  const int blk = blockIdx.x;
  const int lt = blk & 63;
  const int bx = blk >> 6;
  const int b = bx >> 2, x = bx & 3;
  const int l0 = lt * 16;
  for (int i = 0; i < 2; ++i) {
    int f = t + i * 256;
    int r = f >> 5, c4 = f & 31;
    float4 v = *(const float4*)(q + ((size_t)((b * L + l0 + r) * X + x)) * E + c4 * 4);
    *(float4*)&Qt[r][c4 * 4] = v;
  }
  const int l = t >> 4;
  const int kk = t & 15;
  for (int sc = 0; sc < 16; ++sc) {
    __syncthreads();
    for (int i = 0; i < 8; ++i) {
      int f = t + i * 256;
      int r = f >> 5, c4 = f & 31;
      float4 v = *(const float4*)(k + ((size_t)((b * L + sc * 64 + r) * X + x)) * E + c4 * 4);
      *(float4*)&Kt[r][c4 * 4] = v;
    }
    __syncthreads();
    float d0 = 0.f, d1 = 0.f, d2 = 0.f, d3 = 0.f;
#pragma unroll
    for (int e4 = 0; e4 < 32; ++e4) {
      float4 qv = *(float4*)&Qt[l][e4 * 4];
      float4 k0 = *(float4*)&Kt[kk + 0][e4 * 4];
      float4 k1 = *(float4*)&Kt[kk + 16][e4 * 4];
      float4 k2 = *(float4*)&Kt[kk + 32][e4 * 4];
      float4 k3 = *(float4*)&Kt[kk + 48][e4 * 4];
      d0 += qv.x * k0.x + qv.y * k0.y + qv.z * k0.z + qv.w * k0.w;
      d1 += qv.x * k1.x + qv.y * k1.y + qv.z * k1.z + qv.w * k1.w;
      d2 += qv.x * k2.x + qv.y * k2.y + qv.z * k2.z + qv.w * k2.w;
      d3 += qv.x * k3.x + qv.y * k3.y + qv.z * k3.z + qv.w * k3.w;
    }
    float* o = sb + ((size_t)(bx * L + l0 + l)) * L + sc * 64 + kk;
    o[0] = d0 * SCALE; o[16] = d1 * SCALE; o[32] = d2 * SCALE; o[48] = d3 * SCALE;
  }
}

// ---------------- K2: row softmax over s (in place) ---------------------------------
__global__ __launch_bounds__(256) void k2_softmax(float* __restrict__ sb) {
  __shared__ float red[4];
  const int t = threadIdx.x;
  float* p = sb + (size_t)blockIdx.x * L;
  float4 v = ((float4*)p)[t];
  float mx = fmaxf(fmaxf(v.x, v.y), fmaxf(v.z, v.w));
#pragma unroll
  for (int o = 32; o > 0; o >>= 1) mx = fmaxf(mx, __shfl_down(mx, o, 64));
  if ((t & 63) == 0) red[t >> 6] = mx;
  __syncthreads();
  mx = fmaxf(fmaxf(red[0], red[1]), fmaxf(red[2], red[3]));
  __syncthreads();
  v.x = expf(v.x - mx); v.y = expf(v.y - mx);
  v.z = expf(v.z - mx); v.w = expf(v.w - mx);
  float s = v.x + v.y + v.z + v.w;
#pragma unroll
  for (int o = 32; o > 0; o >>= 1) s += __shfl_down(s, o, 64);
  if ((t & 63) == 0) red[t >> 6] = s;
  __syncthreads();
  s = red[0] + red[1] + red[2] + red[3];
  float inv = 1.0f / s;
  v.x *= inv; v.y *= inv; v.z *= inv; v.w *= inv;
  ((float4*)p)[t] = v;
}

// ---------------- K3: Retr[bxy,l,e] = sum_s Search[b,x,l,s] * value[b,s,y,e] --------
__global__ __launch_bounds__(256) void k3_retr(const float* __restrict__ sb,
                                               const float* __restrict__ value,
                                               float* __restrict__ rb) {
  __shared__ float Pt[32][36];
  __shared__ float Vt[32][132];
  const int t = threadIdx.x;
  const int blk = blockIdx.x;
  const int lt = blk & 31;
  const int bxy = blk >> 5;
  const int b = bxy >> 4;
  const int y = bxy & 3;
  const int l0 = lt * 32;
  const int srow = (bxy >> 2) * L;
  const int l = t >> 3;
  const int e0 = (t & 7) << 4;
  float acc[16];
#pragma unroll
  for (int i = 0; i < 16; ++i) acc[i] = 0.f;
  for (int scn = 0; scn < 32; ++scn) {
    __syncthreads();
    {
      int r = t >> 3, c4 = t & 7;
      float4 pv = *(const float4*)(sb + ((size_t)(srow + l0 + r)) * L + scn * 32 + c4 * 4);
      *(float4*)&Pt[r][c4 * 4] = pv;
    }
#pragma unroll
    for (int i = 0; i < 4; ++i) {
      int f = t + i * 256;
      int r = f >> 5, c4 = f & 31;
      float4 vv = *(const float4*)(value + ((size_t)((b * L + scn * 32 + r) * Y + y)) * E + c4 * 4);
      *(float4*)&Vt[r][c4 * 4] = vv;
    }
    __syncthreads();
#pragma unroll 8
    for (int s = 0; s < 32; ++s) {
      float pw = Pt[l][s];
      float4 v0 = *(float4*)&Vt[s][e0 + 0];
      float4 v1 = *(float4*)&Vt[s][e0 + 4];
      float4 v2 = *(float4*)&Vt[s][e0 + 8];
      float4 v3 = *(float4*)&Vt[s][e0 + 12];
      acc[0] += pw * v0.x; acc[1] += pw * v0.y; acc[2] += pw * v0.z; acc[3] += pw * v0.w;
      acc[4] += pw * v1.x; acc[5] += pw * v1.y; acc[6] += pw * v1.z; acc[7] += pw * v1.w;
      acc[8] += pw * v2.x; acc[9] += pw * v2.y; acc[10] += pw * v2.z; acc[11] += pw * v2.w;
      acc[12] += pw * v3.x; acc[13] += pw * v3.y; acc[14] += pw * v3.z; acc[15] += pw * v3.w;
    }
  }
  float* o = rb + ((size_t)(bxy * L + l0 + l)) * E + e0;
  *(float4*)(o + 0) = make_float4(acc[0], acc[1], acc[2], acc[3]);
  *(float4*)(o + 4) = make_float4(acc[4], acc[5], acc[6], acc[7]);
  *(float4*)(o + 8) = make_float4(acc[8], acc[9], acc[10], acc[11]);
  *(float4*)(o + 12) = make_float4(acc[12], acc[13], acc[14], acc[15]);
}

// ---------------- K4: kp_bf[bxy,m,f] (bf16) = R.Wk^T + bk ; rt_bf[bxy,e,m] = R^T bf16
__global__ __launch_bounds__(256) void k4_kp(const float* __restrict__ rb,
                                             const float* __restrict__ Wk,
                                             const float* __restrict__ bk,
                                             u16* __restrict__ kp_bf,
                                             u16* __restrict__ rt_bf) {
  __shared__ float Rt[32][132];
  __shared__ float Wt[128][36];
  const int t = threadIdx.x;
  const int blk = blockIdx.x;
  const int lt = blk & 31;
  const int bxy = blk >> 5;
  const int l0 = lt * 32;
#pragma unroll
  for (int i = 0; i < 4; ++i) {
    int f = t + i * 256;
    int r = f >> 5, c4 = f & 31;
    *(float4*)&Rt[r][c4 * 4] = *(const float4*)(rb + ((size_t)(bxy * L + l0 + r)) * E + c4 * 4);
  }
  const int m = t >> 3;
  const int fs = (t & 7) << 2;
  for (int ft = 0; ft < 4; ++ft) {
    __syncthreads();
#pragma unroll
    for (int i = 0; i < 4; ++i) {
      int f = t + i * 256;
      int fj = f >> 5, c4 = f & 31;
      float4 wv = *(const float4*)(Wk + (ft * 32 + fj) * E + c4 * 4);
      Wt[c4 * 4 + 0][fj] = wv.x;
      Wt[c4 * 4 + 1][fj] = wv.y;
      Wt[c4 * 4 + 2][fj] = wv.z;
      Wt[c4 * 4 + 3][fj] = wv.w;
    }
    __syncthreads();
    float a0 = 0.f, a1 = 0.f, a2 = 0.f, a3 = 0.f;
#pragma unroll 16
    for (int e = 0; e < 128; ++e) {
      float rv = Rt[m][e];
      float4 wv = *(float4*)&Wt[e][fs];
      a0 += rv * wv.x; a1 += rv * wv.y; a2 += rv * wv.z; a3 += rv * wv.w;
    }
    int fb = ft * 32 + fs;
    ushort4 o4 = make_ushort4(bfr(a0 + bk[fb]), bfr(a1 + bk[fb + 1]),
                              bfr(a2 + bk[fb + 2]), bfr(a3 + bk[fb + 3]));
    *(ushort4*)(kp_bf + ((size_t)(bxy * L + l0 + m)) * E + fb) = o4;
  }
  // transpose epilogue: rt_bf[bxy][e][l] from the staged R tile
  {
    const int e = t >> 1, half = t & 1;
    u16 us[16];
#pragma unroll
    for (int j = 0; j < 16; ++j) us[j] = bfr(Rt[half * 16 + j][e]);
    u16* dst = rt_bf + ((size_t)(bxy * E + e)) * L + l0 + half * 16;
    *(uint4*)dst = *(uint4*)&us[0];
    *(uint4*)(dst + 8) = *(uint4*)&us[8];
  }
}

// ---------------- K5: fused stage 2 via MFMA bf16 -----------------------------------
// Per block: (b,x, 32 l-rows, 1/8 of m). Wave w: S-tile (lw=w>>1, mt=w&1);
// softmax over y fully in-register on C-frags; P -> LDS (A-layout); PV accumulates
// V C-frags (lw, 4 e-tiles selected by w&1).
__global__ __launch_bounds__(256) void k5_stage2(const float* __restrict__ qp,
                                                 const u16* __restrict__ kp_bf,
                                                 const u16* __restrict__ rt_bf,
                                                 float* __restrict__ vws) {
  __shared__ __align__(16) u16 qpT[32][136];
  __shared__ __align__(16) u16 kpT[32][136];
  __shared__ __align__(16) u16 rtT[128][40];
  __shared__ __align__(16) u16 pT[4][32][40];
  const int t = threadIdx.x;
  const int blk = blockIdx.x;
  const int part = blk & 7;
  const int lt = (blk >> 3) & 31;
  const int bx = blk >> 8;
  const int b = bx >> 2, x = bx & 3;
  const int l0 = lt * 32;
  const int lane = t & 63;
  const int w = t >> 6;
  const int col = lane & 15;
  const int quad = lane >> 4;
  const int lw = w >> 1;   // l-tile (both phases)
  const int mt = w & 1;    // m-tile (S phase)
  const int eg = w & 1;    // e-group (PV phase)

  // stage qp -> bf16 LDS once
  {
    const int l = t >> 3, e0 = (t & 7) * 16;
    const float* src = qp + (((size_t)((b * L + l0 + l) * X + x)) * E + e0);
    u16 us[16];
#pragma unroll
    for (int i = 0; i < 4; ++i) {
      float4 v = *(const float4*)(src + i * 4);
      us[i * 4 + 0] = bfr(v.x); us[i * 4 + 1] = bfr(v.y);
      us[i * 4 + 2] = bfr(v.z); us[i * 4 + 3] = bfr(v.w);
    }
    *(uint4*)&qpT[l][e0] = *(uint4*)&us[0];
    *(uint4*)&qpT[l][e0 + 8] = *(uint4*)&us[8];
  }
  __syncthreads();
  bf16frag af[4];
#pragma unroll
  for (int k = 0; k < 4; ++k)
    af[k] = *(const bf16frag*)&qpT[lw * 16 + col][k * 32 + quad * 8];

  floatx4 vf[4];
#pragma unroll
  for (int i = 0; i < 4; ++i) vf[i] = (floatx4){0.f, 0.f, 0.f, 0.f};

  const int mc0 = part * 4;
  for (int mc = mc0; mc < mc0 + 4; ++mc) {
    const int m0 = mc * 32;
    floatx4 sf[4];
#pragma unroll
    for (int y = 0; y < 4; ++y) sf[y] = (floatx4){0.f, 0.f, 0.f, 0.f};
    // --- S phase: per y, stage kp tile then 4 MFMA over K=128 ---
    for (int y = 0; y <= x; ++y) {
      __syncthreads();
      {
        const int m = t >> 3, e0 = (t & 7) * 16;
        const u16* src = kp_bf + (((size_t)(bx * 4 + y) * L + m0 + m)) * E + e0;
        uint4 a0 = *(const uint4*)src;
        uint4 a1 = *(const uint4*)(src + 8);
        *(uint4*)&kpT[m][e0] = a0;
        *(uint4*)&kpT[m][e0 + 8] = a1;
      }
      __syncthreads();
#pragma unroll
      for (int k = 0; k < 4; ++k) {
        bf16frag bfv = *(const bf16frag*)&kpT[mt * 16 + col][k * 32 + quad * 8];
        sf[y] = __builtin_amdgcn_mfma_f32_16x16x32_bf16(af[k], bfv, sf[y], 0, 0, 0);
      }
    }
    // --- softmax over y, elementwise per C-frag register ---
    u16 pu[4][4];
#pragma unroll
    for (int r = 0; r < 4; ++r) {
      float zz[4];
      float mx = -3.4e38f;
      for (int y = 0; y <= x; ++y) { zz[y] = sf[y][r] * SCALE; mx = fmaxf(mx, zz[y]); }
      float sum = 0.f;
      for (int y = 0; y <= x; ++y) { zz[y] = __expf(zz[y] - mx); sum += zz[y]; }
      float inv = 1.0f / sum;
      for (int y = 0; y <= x; ++y) pu[y][r] = bfr(zz[y] * inv);
    }
    __syncthreads();  // previous mc's PV reads of pT complete
#pragma unroll 1
    for (int y = 0; y <= x; ++y)
#pragma unroll
      for (int r = 0; r < 4; ++r)
        pT[y][lw * 16 + quad * 4 + r][mt * 16 + col] = pu[y][r];
    // --- PV phase: per y, stage R^T tile then 4 MFMA (one per e-tile) ---
    for (int y = 0; y <= x; ++y) {
      __syncthreads();
      {
        const int e = t >> 1, half = t & 1;
        const u16* src = rt_bf + (((size_t)(bx * 4 + y) * E + e)) * L + m0 + half * 16;
        uint4 a0 = *(const uint4*)src;
        uint4 a1 = *(const uint4*)(src + 8);
        *(uint4*)&rtT[e][half * 16] = a0;
        *(uint4*)&rtT[e][half * 16 + 8] = a1;
      }
      __syncthreads();
      bf16frag pf = *(const bf16frag*)&pT[y][lw * 16 + col][quad * 8];
#pragma unroll
      for (int i = 0; i < 4; ++i) {
        const int et = eg * 4 + i;
        bf16frag rf = *(const bf16frag*)&rtT[et * 16 + col][quad * 8];
        vf[i] = __builtin_amdgcn_mfma_f32_16x16x32_bf16(pf, rf, vf[i], 0, 0, 0);
      }
    }
  }
  // epilogue: vws[part][b][x][l][e], coalesced (col spans 16 consecutive e)
  float* dst = vws + (size_t)part * (B * L * 512) + ((size_t)bx * L + l0) * E;
#pragma unroll
  for (int i = 0; i < 4; ++i)
#pragma unroll
    for (int r = 0; r < 4; ++r)
      dst[((size_t)(lw * 16 + quad * 4 + r)) * E + (eg * 4 + i) * 16 + col] = vf[i][r];
}

// ---------------- K6: sum 8 partials, reorder (x,e)->flat(e*4+x), project with Wv ---
__global__ __launch_bounds__(256) void k6_vout(const float* __restrict__ vws,
                                               const float* __restrict__ Wv,
                                               const float* __restrict__ bv,
                                               float* __restrict__ vout) {
  __shared__ float rowx[4][132];
  const int t = threadIdx.x;
  const int bl = blockIdx.x;  // b*L + l
  {
    const int o = t * 2;
    const int xh = o >> 7, e = o & 127;
    const int b = bl >> 10, l = bl & 1023;
    const size_t base = ((size_t)((b * 4 + xh) * 1024 + l)) * 128 + e;
    float sx = 0.f, sy = 0.f;
#pragma unroll
    for (int p = 0; p < 8; ++p) {
      float2 v = *(const float2*)(vws + (size_t)p * 1048576 + base);
      sx += v.x; sy += v.y;
    }
    rowx[xh][e] = sx; rowx[xh][e + 1] = sy;
  }
  __syncthreads();
#pragma unroll
  for (int rep = 0; rep < 2; ++rep) {
    const int o = t + rep * 256;
    const int s = o >> 7, f = o & 127;
    const float4* wr = (const float4*)(Wv + f * E);
    float acc = 0.f;
#pragma unroll 8
    for (int e4 = 0; e4 < 32; ++e4) {
      float4 wv = wr[e4];
      acc += wv.x * rowx[0][s * 32 + e4] + wv.y * rowx[1][s * 32 + e4]
           + wv.z * rowx[2][s * 32 + e4] + wv.w * rowx[3][s * 32 + e4];
    }
    vout[(size_t)bl * 512 + o] = acc + bv[f];
  }
}

// ---------------- K7: Gaussian prior + sig output (f64 sigma chain for accuracy) ----
__global__ __launch_bounds__(256) void k7_prior(const float* __restrict__ sigma,
                                                float* __restrict__ prior,
                                                float* __restrict__ sigout) {
  const int row = blockIdx.x;
  const int bx = row >> 10;
  const int i = row & 1023;
  const int b = bx >> 2, x = bx & 3;
  const double sv = (double)sigma[((size_t)(b * L + i)) * X + x];
  const double sg = 1.0 / (1.0 + exp(-5.0 * sv)) + 1e-5;
  const double s3 = exp(sg * 1.0986122886681098) - 1.0;
  const float coef = (float)(1.0 / (2.5066282746310002 * s3));
  const float inv2s2 = (float)(0.5 / (s3 * s3));
  const int t = threadIdx.x;
  const float di = (float)i;
  const int j0 = t * 4;
  float4 o; float d;
  d = di - (float)(j0 + 0); o.x = coef * expf(-d * d * inv2s2);
  d = di - (float)(j0 + 1); o.y = coef * expf(-d * d * inv2s2);
  d = di - (float)(j0 + 2); o.z = coef * expf(-d * d * inv2s2);
  d = di - (float)(j0 + 3); o.w = coef * expf(-d * d * inv2s2);
  *(float4*)(prior + (size_t)row * 1024 + j0) = o;
  if (t == 0) sigout[row] = (float)s3;
}

extern "C" void kernel_launch(void* const* d_in, const int* in_sizes, int n_in,
                              void* d_out, int out_size, void* d_ws, size_t ws_size,
                              hipStream_t stream) {
  const float* q     = (const float*)d_in[1];
  const float* key   = (const float*)d_in[2];
  const float* value = (const float*)d_in[3];
  const float* sigma = (const float*)d_in[4];
  const float* qp    = (const float*)d_in[8];
  const float* Wk    = (const float*)d_in[9];
  const float* bk    = (const float*)d_in[10];
  const float* Wv    = (const float*)d_in[11];
  const float* bv    = (const float*)d_in[12];

  float* out    = (float*)d_out;
  float* Vout   = out;
  float* sout   = out + 1048576;
  float* prior  = out + 9437184;
  float* sigout = out + 17825792;

  // ws layout (floats). Lifetimes: sb [0,8M) k1..k3; rb [8M,12M) k3..k4;
  // kp_bf [0,2M) + rt_bf [2M,4M) k4..k5 (overlay dead sb); vws [4M,12M) k5..k6.
  float* ws    = (float*)d_ws;
  float* sb    = ws;
  float* rb    = ws + 8388608;
  u16*   kp_bf = (u16*)ws;
  u16*   rt_bf = (u16*)(ws + 2097152);
  float* vws   = ws + 4194304;

  hipLaunchKernelGGL(k0_fill,    dim3(8192), dim3(256), 0, stream, (float4*)sout, 2097152);
  hipLaunchKernelGGL(k1_scores,  dim3(512),  dim3(256), 0, stream, q, key, sb);
  hipLaunchKernelGGL(k2_softmax, dim3(8192), dim3(256), 0, stream, sb);
  hipLaunchKernelGGL(k3_retr,    dim3(1024), dim3(256), 0, stream, sb, value, rb);
  hipLaunchKernelGGL(k4_kp,      dim3(1024), dim3(256), 0, stream, rb, Wk, bk, kp_bf, rt_bf);
  hipLaunchKernelGGL(k5_stage2,  dim3(2048), dim3(256), 0, stream, qp, kp_bf, rt_bf, vws);
  hipLaunchKernelGGL(k6_vout,    dim3(2048), dim3(256), 0, stream, vws, Wv, bv, Vout);
  hipLaunchKernelGGL(k7_prior,   dim3(8192), dim3(256), 0, stream, sigma, prior, sigout);
}

// Round 5
// 481.581 us; speedup vs baseline: 2.4583x; 1.4307x over previous
//
#include <hip/hip_runtime.h>
#include <math.h>

#define B 2
#define L 1024
#define X 4
#define E 128
#define Y 4
#define SCALE 0.08838834764831845f  // 1/sqrt(128)

typedef unsigned short u16;
typedef __attribute__((ext_vector_type(8))) short bf16frag;   // 8 bf16 (4 VGPRs)
typedef __attribute__((ext_vector_type(4))) float floatx4;    // 4 fp32 acc

// round-to-nearest-even f32 -> bf16
static __device__ __forceinline__ u16 bfr(float f) {
  union { float f; unsigned u; } c; c.f = f;
  unsigned r = (c.u + 0x7fffu + ((c.u >> 16) & 1u)) >> 16;
  return (u16)r;
}

// ---------------- K0: series_out is identically 0.25 (mean over the softmax axis) ----
__global__ __launch_bounds__(256) void k0_fill(float4* __restrict__ p, int n4) {
  int i = blockIdx.x * 256 + threadIdx.x;
  if (i < n4) p[i] = make_float4(0.25f, 0.25f, 0.25f, 0.25f);
}

// ---------------- K1: scores[b,x,l,s] = scale * <q[b,l,x,:], key[b,s,x,:]> ----------
// (verbatim from the R2-passing version)
__global__ __launch_bounds__(256) void k1_scores(const float* __restrict__ q,
                                                 const float* __restrict__ k,
                                                 float* __restrict__ sb) {
  __shared__ float Qt[16][132];
  __shared__ float Kt[64][132];
  const int t = threadIdx.x;
  const int blk = blockIdx.x;
  const int lt = blk & 63;
  const int bx = blk >> 6;
  const int b = bx >> 2, x = bx & 3;
  const int l0 = lt * 16;
  for (int i = 0; i < 2; ++i) {
    int f = t + i * 256;
    int r = f >> 5, c4 = f & 31;
    float4 v = *(const float4*)(q + ((size_t)((b * L + l0 + r) * X + x)) * E + c4 * 4);
    *(float4*)&Qt[r][c4 * 4] = v;
  }
  const int l = t >> 4;
  const int kk = t & 15;
  for (int sc = 0; sc < 16; ++sc) {
    __syncthreads();
    for (int i = 0; i < 8; ++i) {
      int f = t + i * 256;
      int r = f >> 5, c4 = f & 31;
      float4 v = *(const float4*)(k + ((size_t)((b * L + sc * 64 + r) * X + x)) * E + c4 * 4);
      *(float4*)&Kt[r][c4 * 4] = v;
    }
    __syncthreads();
    float d0 = 0.f, d1 = 0.f, d2 = 0.f, d3 = 0.f;
#pragma unroll
    for (int e4 = 0; e4 < 32; ++e4) {
      float4 qv = *(float4*)&Qt[l][e4 * 4];
      float4 k0 = *(float4*)&Kt[kk + 0][e4 * 4];
      float4 k1 = *(float4*)&Kt[kk + 16][e4 * 4];
      float4 k2 = *(float4*)&Kt[kk + 32][e4 * 4];
      float4 k3 = *(float4*)&Kt[kk + 48][e4 * 4];
      d0 += qv.x * k0.x + qv.y * k0.y + qv.z * k0.z + qv.w * k0.w;
      d1 += qv.x * k1.x + qv.y * k1.y + qv.z * k1.z + qv.w * k1.w;
      d2 += qv.x * k2.x + qv.y * k2.y + qv.z * k2.z + qv.w * k2.w;
      d3 += qv.x * k3.x + qv.y * k3.y + qv.z * k3.z + qv.w * k3.w;
    }
    float* o = sb + ((size_t)(bx * L + l0 + l)) * L + sc * 64 + kk;
    o[0] = d0 * SCALE; o[16] = d1 * SCALE; o[32] = d2 * SCALE; o[48] = d3 * SCALE;
  }
}

// ---------------- K2: row softmax over s -> bf16 output (verbatim R2) ---------------
__global__ __launch_bounds__(256) void k2_softmax(const float* __restrict__ sb,
                                                  u16* __restrict__ sbh) {
  __shared__ float red[4];
  const int t = threadIdx.x;
  const float* p = sb + (size_t)blockIdx.x * L;
  float4 v = ((const float4*)p)[t];
  float mx = fmaxf(fmaxf(v.x, v.y), fmaxf(v.z, v.w));
#pragma unroll
  for (int o = 32; o > 0; o >>= 1) mx = fmaxf(mx, __shfl_down(mx, o, 64));
  if ((t & 63) == 0) red[t >> 6] = mx;
  __syncthreads();
  mx = fmaxf(fmaxf(red[0], red[1]), fmaxf(red[2], red[3]));
  __syncthreads();
  v.x = expf(v.x - mx); v.y = expf(v.y - mx);
  v.z = expf(v.z - mx); v.w = expf(v.w - mx);
  float s = v.x + v.y + v.z + v.w;
#pragma unroll
  for (int o = 32; o > 0; o >>= 1) s += __shfl_down(s, o, 64);
  if ((t & 63) == 0) red[t >> 6] = s;
  __syncthreads();
  s = red[0] + red[1] + red[2] + red[3];
  float inv = 1.0f / s;
  ushort4 o4 = make_ushort4(bfr(v.x * inv), bfr(v.y * inv), bfr(v.z * inv), bfr(v.w * inv));
  ((ushort4*)(sbh + (size_t)blockIdx.x * L))[t] = o4;
}

// ---------------- K2v: vt[(b*4+y)*128+e][s] = bf16(value[b,s,y,e]) ------------------
// NOTE: vt overlays dead sb head -> must launch AFTER k2.
__global__ __launch_bounds__(128) void k2v_transpose(const float* __restrict__ value,
                                                     u16* __restrict__ vt) {
  const int blk = blockIdx.x;       // by*32 + sc
  const int sc = blk & 31, by = blk >> 5;
  const int b = by >> 2, y = by & 3;
  const int t = threadIdx.x;        // e
  const int s0 = sc * 32;
  u16 us[32];
#pragma unroll 8
  for (int ss = 0; ss < 32; ++ss)
    us[ss] = bfr(value[((size_t)((b * L + s0 + ss) * Y + y)) * E + t]);
  u16* dst = vt + ((size_t)(by * E + t)) * L + s0;
#pragma unroll
  for (int i = 0; i < 4; ++i) *(uint4*)(dst + i * 8) = *(uint4*)&us[i * 8];
}

// ---------------- K3: Retr[bxy,l,e] = sum_s P[bx,l,s] * V[b,s,y,e] via MFMA ---------
__global__ __launch_bounds__(256) void k3_retr(const u16* __restrict__ sbh,
                                               const u16* __restrict__ vt,
                                               float* __restrict__ rb) {
  __shared__ __align__(16) u16 Pt[32][40];
  __shared__ __align__(16) u16 Vt[128][40];
  const int t = threadIdx.x;
  const int blk = blockIdx.x;
  const int lt = blk & 31;
  const int bxy = blk >> 5;                    // ((b*4+x)*4+y)
  const int by = (bxy >> 4) * 4 + (bxy & 3);   // b*4+y (vt batch)
  const int srow = (bxy >> 2) * L;             // (b*4+x)*L (Search batch)
  const int l0 = lt * 32;
  const int lane = t & 63, w = t >> 6;
  const int col = lane & 15, quad = lane >> 4;
  const int lw = w >> 1, eg = w & 1;
  floatx4 vf[4];
#pragma unroll
  for (int i = 0; i < 4; ++i) vf[i] = (floatx4){0.f, 0.f, 0.f, 0.f};
  for (int sc = 0; sc < 32; ++sc) {
    const int s0 = sc * 32;
    __syncthreads();
    {  // stage P tile 32l x 32s
      const int r = t >> 3, c = (t & 7) * 4;
      *(uint2*)&Pt[r][c] = *(const uint2*)(sbh + (size_t)(srow + l0 + r) * L + s0 + c);
    }
    {  // stage V^T tile 128e x 32s
      const int e = t >> 1, half = (t & 1) * 16;
      const u16* src = vt + ((size_t)(by * E + e)) * L + s0 + half;
      *(uint4*)&Vt[e][half] = *(const uint4*)src;
      *(uint4*)&Vt[e][half + 8] = *(const uint4*)(src + 8);
    }
    __syncthreads();
    bf16frag pf = *(const bf16frag*)&Pt[lw * 16 + col][quad * 8];
#pragma unroll
    for (int i = 0; i < 4; ++i) {
      bf16frag rf = *(const bf16frag*)&Vt[(eg * 4 + i) * 16 + col][quad * 8];
      vf[i] = __builtin_amdgcn_mfma_f32_16x16x32_bf16(pf, rf, vf[i], 0, 0, 0);
    }
  }
  float* dst = rb + ((size_t)(bxy * L + l0 + lw * 16)) * E + eg * 64;
#pragma unroll
  for (int i = 0; i < 4; ++i)
#pragma unroll
    for (int r = 0; r < 4; ++r)
      dst[(size_t)(quad * 4 + r) * E + i * 16 + col] = vf[i][r];
}

// ---------------- K4: kp_bf[bxy,m,f] (bf16) = R.Wk^T + bk ; rt_bf[bxy,e,m] = R^T bf16
__global__ __launch_bounds__(256) void k4_kp(const float* __restrict__ rb,
                                             const float* __restrict__ Wk,
                                             const float* __restrict__ bk,
                                             u16* __restrict__ kp_bf,
                                             u16* __restrict__ rt_bf) {
  __shared__ float Rt[32][132];
  __shared__ float Wt[128][36];
  const int t = threadIdx.x;
  const int blk = blockIdx.x;
  const int lt = blk & 31;
  const int bxy = blk >> 5;
  const int l0 = lt * 32;
#pragma unroll
  for (int i = 0; i < 4; ++i) {
    int f = t + i * 256;
    int r = f >> 5, c4 = f & 31;
    *(float4*)&Rt[r][c4 * 4] = *(const float4*)(rb + ((size_t)(bxy * L + l0 + r)) * E + c4 * 4);
  }
  const int m = t >> 3;
  const int fs = (t & 7) << 2;
  for (int ft = 0; ft < 4; ++ft) {
    __syncthreads();
#pragma unroll
    for (int i = 0; i < 4; ++i) {
      int f = t + i * 256;
      int fj = f >> 5, c4 = f & 31;
      float4 wv = *(const float4*)(Wk + (ft * 32 + fj) * E + c4 * 4);
      Wt[c4 * 4 + 0][fj] = wv.x;
      Wt[c4 * 4 + 1][fj] = wv.y;
      Wt[c4 * 4 + 2][fj] = wv.z;
      Wt[c4 * 4 + 3][fj] = wv.w;
    }
    __syncthreads();
    float a0 = 0.f, a1 = 0.f, a2 = 0.f, a3 = 0.f;
#pragma unroll 16
    for (int e = 0; e < 128; ++e) {
      float rv = Rt[m][e];
      float4 wv = *(float4*)&Wt[e][fs];
      a0 += rv * wv.x; a1 += rv * wv.y; a2 += rv * wv.z; a3 += rv * wv.w;
    }
    int fb = ft * 32 + fs;
    ushort4 o4 = make_ushort4(bfr(a0 + bk[fb]), bfr(a1 + bk[fb + 1]),
                              bfr(a2 + bk[fb + 2]), bfr(a3 + bk[fb + 3]));
    *(ushort4*)(kp_bf + ((size_t)(bxy * L + l0 + m)) * E + fb) = o4;
  }
  // transpose epilogue: rt_bf[bxy][e][l] from the staged R tile
  {
    const int e = t >> 1, half = t & 1;
    u16 us[16];
#pragma unroll
    for (int j = 0; j < 16; ++j) us[j] = bfr(Rt[half * 16 + j][e]);
    u16* dst = rt_bf + ((size_t)(bxy * E + e)) * L + l0 + half * 16;
    *(uint4*)dst = *(uint4*)&us[0];
    *(uint4*)(dst + 8) = *(uint4*)&us[8];
  }
}

// ---------------- K5: fused stage 2 via MFMA bf16 (verbatim R2) ---------------------
__global__ __launch_bounds__(256) void k5_stage2(const float* __restrict__ qp,
                                                 const u16* __restrict__ kp_bf,
                                                 const u16* __restrict__ rt_bf,
                                                 float* __restrict__ vws) {
  __shared__ __align__(16) u16 qpT[32][136];
  __shared__ __align__(16) u16 kpT[32][136];
  __shared__ __align__(16) u16 rtT[128][40];
  __shared__ __align__(16) u16 pT[4][32][40];
  const int t = threadIdx.x;
  const int blk = blockIdx.x;
  const int part = blk & 7;
  const int lt = (blk >> 3) & 31;
  const int bx = blk >> 8;
  const int b = bx >> 2, x = bx & 3;
  const int l0 = lt * 32;
  const int lane = t & 63;
  const int w = t >> 6;
  const int col = lane & 15;
  const int quad = lane >> 4;
  const int lw = w >> 1;
  const int mt = w & 1;
  const int eg = w & 1;

  {
    const int l = t >> 3, e0 = (t & 7) * 16;
    const float* src = qp + (((size_t)((b * L + l0 + l) * X + x)) * E + e0);
    u16 us[16];
#pragma unroll
    for (int i = 0; i < 4; ++i) {
      float4 v = *(const float4*)(src + i * 4);
      us[i * 4 + 0] = bfr(v.x); us[i * 4 + 1] = bfr(v.y);
      us[i * 4 + 2] = bfr(v.z); us[i * 4 + 3] = bfr(v.w);
    }
    *(uint4*)&qpT[l][e0] = *(uint4*)&us[0];
    *(uint4*)&qpT[l][e0 + 8] = *(uint4*)&us[8];
  }
  __syncthreads();
  bf16frag af[4];
#pragma unroll
  for (int k = 0; k < 4; ++k)
    af[k] = *(const bf16frag*)&qpT[lw * 16 + col][k * 32 + quad * 8];

  floatx4 vf[4];
#pragma unroll
  for (int i = 0; i < 4; ++i) vf[i] = (floatx4){0.f, 0.f, 0.f, 0.f};

  const int mc0 = part * 4;
  for (int mc = mc0; mc < mc0 + 4; ++mc) {
    const int m0 = mc * 32;
    floatx4 sf[4];
#pragma unroll
    for (int y = 0; y < 4; ++y) sf[y] = (floatx4){0.f, 0.f, 0.f, 0.f};
    for (int y = 0; y <= x; ++y) {
      __syncthreads();
      {
        const int m = t >> 3, e0 = (t & 7) * 16;
        const u16* src = kp_bf + (((size_t)(bx * 4 + y) * L + m0 + m)) * E + e0;
        uint4 a0 = *(const uint4*)src;
        uint4 a1 = *(const uint4*)(src + 8);
        *(uint4*)&kpT[m][e0] = a0;
        *(uint4*)&kpT[m][e0 + 8] = a1;
      }
      __syncthreads();
#pragma unroll
      for (int k = 0; k < 4; ++k) {
        bf16frag bfv = *(const bf16frag*)&kpT[mt * 16 + col][k * 32 + quad * 8];
        sf[y] = __builtin_amdgcn_mfma_f32_16x16x32_bf16(af[k], bfv, sf[y], 0, 0, 0);
      }
    }
    u16 pu[4][4];
#pragma unroll
    for (int r = 0; r < 4; ++r) {
      float zz[4];
      float mx = -3.4e38f;
      for (int y = 0; y <= x; ++y) { zz[y] = sf[y][r] * SCALE; mx = fmaxf(mx, zz[y]); }
      float sum = 0.f;
      for (int y = 0; y <= x; ++y) { zz[y] = __expf(zz[y] - mx); sum += zz[y]; }
      float inv = 1.0f / sum;
      for (int y = 0; y <= x; ++y) pu[y][r] = bfr(zz[y] * inv);
    }
    __syncthreads();
#pragma unroll 1
    for (int y = 0; y <= x; ++y)
#pragma unroll
      for (int r = 0; r < 4; ++r)
        pT[y][lw * 16 + quad * 4 + r][mt * 16 + col] = pu[y][r];
    for (int y = 0; y <= x; ++y) {
      __syncthreads();
      {
        const int e = t >> 1, half = t & 1;
        const u16* src = rt_bf + (((size_t)(bx * 4 + y) * E + e)) * L + m0 + half * 16;
        uint4 a0 = *(const uint4*)src;
        uint4 a1 = *(const uint4*)(src + 8);
        *(uint4*)&rtT[e][half * 16] = a0;
        *(uint4*)&rtT[e][half * 16 + 8] = a1;
      }
      __syncthreads();
      bf16frag pf = *(const bf16frag*)&pT[y][lw * 16 + col][quad * 8];
#pragma unroll
      for (int i = 0; i < 4; ++i) {
        const int et = eg * 4 + i;
        bf16frag rf = *(const bf16frag*)&rtT[et * 16 + col][quad * 8];
        vf[i] = __builtin_amdgcn_mfma_f32_16x16x32_bf16(pf, rf, vf[i], 0, 0, 0);
      }
    }
  }
  float* dst = vws + (size_t)part * (B * L * 512) + ((size_t)bx * L + l0) * E;
#pragma unroll
  for (int i = 0; i < 4; ++i)
#pragma unroll
    for (int r = 0; r < 4; ++r)
      dst[((size_t)(lw * 16 + quad * 4 + r)) * E + (eg * 4 + i) * 16 + col] = vf[i][r];
}

// ---------------- K6: sum 8 partials, reorder (x,e)->flat(e*4+x), project with Wv ---
__global__ __launch_bounds__(256) void k6_vout(const float* __restrict__ vws,
                                               const float* __restrict__ Wv,
                                               const float* __restrict__ bv,
                                               float* __restrict__ vout) {
  __shared__ float rowx[4][132];
  const int t = threadIdx.x;
  const int bl = blockIdx.x;
  {
    const int o = t * 2;
    const int xh = o >> 7, e = o & 127;
    const int b = bl >> 10, l = bl & 1023;
    const size_t base = ((size_t)((b * 4 + xh) * 1024 + l)) * 128 + e;
    float sx = 0.f, sy = 0.f;
#pragma unroll
    for (int p = 0; p < 8; ++p) {
      float2 v = *(const float2*)(vws + (size_t)p * 1048576 + base);
      sx += v.x; sy += v.y;
    }
    rowx[xh][e] = sx; rowx[xh][e + 1] = sy;
  }
  __syncthreads();
#pragma unroll
  for (int rep = 0; rep < 2; ++rep) {
    const int o = t + rep * 256;
    const int s = o >> 7, f = o & 127;
    const float4* wr = (const float4*)(Wv + f * E);
    float acc = 0.f;
#pragma unroll 8
    for (int e4 = 0; e4 < 32; ++e4) {
      float4 wv = wr[e4];
      acc += wv.x * rowx[0][s * 32 + e4] + wv.y * rowx[1][s * 32 + e4]
           + wv.z * rowx[2][s * 32 + e4] + wv.w * rowx[3][s * 32 + e4];
    }
    vout[(size_t)bl * 512 + o] = acc + bv[f];
  }
}

// ---------------- K7: Gaussian prior + sig output (f64 sigma chain for accuracy) ----
__global__ __launch_bounds__(256) void k7_prior(const float* __restrict__ sigma,
                                                float* __restrict__ prior,
                                                float* __restrict__ sigout) {
  const int row = blockIdx.x;
  const int bx = row >> 10;
  const int i = row & 1023;
  const int b = bx >> 2, x = bx & 3;
  const double sv = (double)sigma[((size_t)(b * L + i)) * X + x];
  const double sg = 1.0 / (1.0 + exp(-5.0 * sv)) + 1e-5;
  const double s3 = exp(sg * 1.0986122886681098) - 1.0;
  const float coef = (float)(1.0 / (2.5066282746310002 * s3));
  const float inv2s2 = (float)(0.5 / (s3 * s3));
  const int t = threadIdx.x;
  const float di = (float)i;
  const int j0 = t * 4;
  float4 o; float d;
  d = di - (float)(j0 + 0); o.x = coef * expf(-d * d * inv2s2);
  d = di - (float)(j0 + 1); o.y = coef * expf(-d * d * inv2s2);
  d = di - (float)(j0 + 2); o.z = coef * expf(-d * d * inv2s2);
  d = di - (float)(j0 + 3); o.w = coef * expf(-d * d * inv2s2);
  *(float4*)(prior + (size_t)row * 1024 + j0) = o;
  if (t == 0) sigout[row] = (float)s3;
}

extern "C" void kernel_launch(void* const* d_in, const int* in_sizes, int n_in,
                              void* d_out, int out_size, void* d_ws, size_t ws_size,
                              hipStream_t stream) {
  const float* q     = (const float*)d_in[1];
  const float* key   = (const float*)d_in[2];
  const float* value = (const float*)d_in[3];
  const float* sigma = (const float*)d_in[4];
  const float* qp    = (const float*)d_in[8];
  const float* Wk    = (const float*)d_in[9];
  const float* bk    = (const float*)d_in[10];
  const float* Wv    = (const float*)d_in[11];
  const float* bv    = (const float*)d_in[12];

  float* out    = (float*)d_out;
  float* Vout   = out;
  float* sout   = out + 1048576;
  float* prior  = out + 9437184;
  float* sigout = out + 17825792;

  // ws layout (float-unit offsets), peak exactly 12,582,912 floats = 48 MB (R1-proven).
  // Lifetimes (launch order k1,k2,k2v,k3,k4,k5,k6):
  //  sb    [0, 8388608)         f32  k1 w, k2 r
  //  sbh   [8388608, 12582912)  u16[8M]  k2 w, k3 r
  //  vt    [0, 524288)          u16[1M]  k2v w (AFTER k2 - overlays dead sb), k3 r
  //  rb    [524288, 4718592)    f32  k3 w, k4 r
  //  kp_bf [8388608, 9437184) rt_bf [9437184, 10485760)  u16[2M] each, k4 w, k5 r
  //        (overlay dead sbh; disjoint from rb)
  //  vws   [0, 8388608)         f32  k5 w, k6 r (overlays dead vt/rb; disjoint kp/rt)
  float* ws    = (float*)d_ws;
  float* sb    = ws;
  u16*   sbh   = (u16*)(ws + 8388608);
  u16*   vt    = (u16*)ws;
  float* rb    = ws + 524288;
  u16*   kp_bf = (u16*)(ws + 8388608);
  u16*   rt_bf = (u16*)(ws + 9437184);
  float* vws   = ws;

  hipLaunchKernelGGL(k0_fill,       dim3(8192), dim3(256), 0, stream, (float4*)sout, 2097152);
  hipLaunchKernelGGL(k1_scores,     dim3(512),  dim3(256), 0, stream, q, key, sb);
  hipLaunchKernelGGL(k2_softmax,    dim3(8192), dim3(256), 0, stream, sb, sbh);
  hipLaunchKernelGGL(k2v_transpose, dim3(256),  dim3(128), 0, stream, value, vt);
  hipLaunchKernelGGL(k3_retr,       dim3(1024), dim3(256), 0, stream, sbh, vt, rb);
  hipLaunchKernelGGL(k4_kp,         dim3(1024), dim3(256), 0, stream, rb, Wk, bk, kp_bf, rt_bf);
  hipLaunchKernelGGL(k5_stage2,     dim3(2048), dim3(256), 0, stream, qp, kp_bf, rt_bf, vws);
  hipLaunchKernelGGL(k6_vout,       dim3(2048), dim3(256), 0, stream, vws, Wv, bv, Vout);
  hipLaunchKernelGGL(k7_prior,      dim3(8192), dim3(256), 0, stream, sigma, prior, sigout);
}

// Round 6
// 427.610 us; speedup vs baseline: 2.7686x; 1.1262x over previous
//
#include <hip/hip_runtime.h>
#include <math.h>

#define B 2
#define L 1024
#define X 4
#define E 128
#define Y 4
#define SCALE 0.08838834764831845f  // 1/sqrt(128)

typedef unsigned short u16;
typedef __attribute__((ext_vector_type(8))) short bf16frag;   // 8 bf16 (4 VGPRs)
typedef __attribute__((ext_vector_type(4))) float floatx4;    // 4 fp32 acc

// round-to-nearest-even f32 -> bf16
static __device__ __forceinline__ u16 bfr(float f) {
  union { float f; unsigned u; } c; c.f = f;
  unsigned r = (c.u + 0x7fffu + ((c.u >> 16) & 1u)) >> 16;
  return (u16)r;
}

// ---------------- K0: series_out is identically 0.25 (mean over the softmax axis) ----
__global__ __launch_bounds__(256) void k0_fill(float4* __restrict__ p, int n4) {
  int i = blockIdx.x * 256 + threadIdx.x;
  if (i < n4) p[i] = make_float4(0.25f, 0.25f, 0.25f, 0.25f);
}

// ---------------- K0q: convert q,key fp32 [b,l,x,e] -> bf16 [bx][l][e] --------------
__global__ __launch_bounds__(256) void k0q_convert(const float* __restrict__ q,
                                                   const float* __restrict__ key,
                                                   u16* __restrict__ qkb) {
  const int f = blockIdx.x * 256 + threadIdx.x;   // 262144 total
  const int row = f >> 4, c8 = (f & 15) * 8;
  const int sel = row >> 13, row2 = row & 8191;   // row2 = b*4096 + l*4 + x
  const int b = row2 >> 12, l = (row2 >> 2) & 1023, x = row2 & 3;
  const float* src = (sel ? key : q) + (size_t)row2 * E + c8;
  float4 v0 = *(const float4*)src;
  float4 v1 = *(const float4*)(src + 4);
  u16 us[8] = {bfr(v0.x), bfr(v0.y), bfr(v0.z), bfr(v0.w),
               bfr(v1.x), bfr(v1.y), bfr(v1.z), bfr(v1.w)};
  u16* dst = qkb + (size_t)(sel * 8192 + (b * 4 + x) * 1024 + l) * E + c8;
  *(uint4*)dst = *(uint4*)us;
}

// ---------------- K1: MFMA QK^T + fused two-pass softmax ----------------------------
// Block = (bx, 16 l-rows), 512 threads = 8 waves (one s-subtile each). Pass 1: raw
// scores -> row max (regs + shfl + LDS combine). Pass 2: recompute, write bf16
// exp(SCALE*(s-max)) unnormalized P, accumulate row sums -> isum = 1/sum.
// k3 folds the normalization into its epilogue.
__global__ __launch_bounds__(512) void k1_mfma(const u16* __restrict__ qb,
                                               const u16* __restrict__ kb,
                                               u16* __restrict__ sbh,
                                               float* __restrict__ isum) {
  __shared__ __align__(16) u16 Qt[16][136];
  __shared__ __align__(16) u16 Kt[128][136];
  __shared__ float red[8][16];
  const int t = threadIdx.x;
  const int blk = blockIdx.x;
  const int lt = blk & 63, bx = blk >> 6;
  const int l0 = lt * 16;
  const int lane = t & 63, w = t >> 6;
  const int col = lane & 15, quad = lane >> 4;
  if (t < 256) {
    const int r = t >> 4, c8 = (t & 15) * 8;
    *(uint4*)&Qt[r][c8] = *(const uint4*)(qb + (size_t)(bx * L + l0 + r) * E + c8);
  }
  __syncthreads();
  bf16frag af[4];
#pragma unroll
  for (int k = 0; k < 4; ++k)
    af[k] = *(const bf16frag*)&Qt[col][k * 32 + quad * 8];

  float rm[4] = {-3.4e38f, -3.4e38f, -3.4e38f, -3.4e38f};
  // ---- pass 1: row max ----
  for (int sc = 0; sc < 8; ++sc) {
    __syncthreads();
    {
      const int r = t >> 2, c = (t & 3) * 32;
      const u16* src = kb + (size_t)(bx * L + sc * 128 + r) * E + c;
#pragma unroll
      for (int i = 0; i < 4; ++i)
        *(uint4*)&Kt[r][c + i * 8] = *(const uint4*)(src + i * 8);
    }
    __syncthreads();
    floatx4 acc = (floatx4){0.f, 0.f, 0.f, 0.f};
#pragma unroll
    for (int k = 0; k < 4; ++k) {
      bf16frag bk = *(const bf16frag*)&Kt[w * 16 + col][k * 32 + quad * 8];
      acc = __builtin_amdgcn_mfma_f32_16x16x32_bf16(af[k], bk, acc, 0, 0, 0);
    }
#pragma unroll
    for (int r = 0; r < 4; ++r) rm[r] = fmaxf(rm[r], acc[r]);
  }
#pragma unroll
  for (int m = 1; m <= 8; m <<= 1)
#pragma unroll
    for (int r = 0; r < 4; ++r) rm[r] = fmaxf(rm[r], __shfl_xor(rm[r], m, 64));
  if (col == 0)
#pragma unroll
    for (int r = 0; r < 4; ++r) red[w][quad * 4 + r] = rm[r];
  __syncthreads();
  float rmc[4];
#pragma unroll
  for (int r = 0; r < 4; ++r) {
    float m = red[0][quad * 4 + r];
#pragma unroll
    for (int j = 1; j < 8; ++j) m = fmaxf(m, red[j][quad * 4 + r]);
    rmc[r] = m;
  }
  // ---- pass 2: exp + write P + row sums ----
  float rs[4] = {0.f, 0.f, 0.f, 0.f};
  for (int sc = 0; sc < 8; ++sc) {
    __syncthreads();
    {
      const int r = t >> 2, c = (t & 3) * 32;
      const u16* src = kb + (size_t)(bx * L + sc * 128 + r) * E + c;
#pragma unroll
      for (int i = 0; i < 4; ++i)
        *(uint4*)&Kt[r][c + i * 8] = *(const uint4*)(src + i * 8);
    }
    __syncthreads();
    floatx4 acc = (floatx4){0.f, 0.f, 0.f, 0.f};
#pragma unroll
    for (int k = 0; k < 4; ++k) {
      bf16frag bk = *(const bf16frag*)&Kt[w * 16 + col][k * 32 + quad * 8];
      acc = __builtin_amdgcn_mfma_f32_16x16x32_bf16(af[k], bk, acc, 0, 0, 0);
    }
    const size_t so = (size_t)sc * 128 + w * 16 + col;
#pragma unroll
    for (int r = 0; r < 4; ++r) {
      float p = __expf((acc[r] - rmc[r]) * SCALE);
      rs[r] += p;
      sbh[(size_t)(bx * L + l0 + quad * 4 + r) * L + so] = bfr(p);
    }
  }
#pragma unroll
  for (int m = 1; m <= 8; m <<= 1)
#pragma unroll
    for (int r = 0; r < 4; ++r) rs[r] += __shfl_xor(rs[r], m, 64);
  __syncthreads();
  if (col == 0)
#pragma unroll
    for (int r = 0; r < 4; ++r) red[w][quad * 4 + r] = rs[r];
  __syncthreads();
  if (w == 0 && col == 0)
#pragma unroll
    for (int r = 0; r < 4; ++r) {
      float s = 0.f;
#pragma unroll
      for (int j = 0; j < 8; ++j) s += red[j][quad * 4 + r];
      isum[bx * L + l0 + quad * 4 + r] = 1.0f / s;
    }
}

// ---------------- K2v: vt[(b*4+y)*128+e][s] = bf16(value[b,s,y,e]) ------------------
__global__ __launch_bounds__(128) void k2v_transpose(const float* __restrict__ value,
                                                     u16* __restrict__ vt) {
  const int blk = blockIdx.x;       // by*32 + sc
  const int sc = blk & 31, by = blk >> 5;
  const int b = by >> 2, y = by & 3;
  const int t = threadIdx.x;        // e
  const int s0 = sc * 32;
  u16 us[32];
#pragma unroll 8
  for (int ss = 0; ss < 32; ++ss)
    us[ss] = bfr(value[((size_t)((b * L + s0 + ss) * Y + y)) * E + t]);
  u16* dst = vt + ((size_t)(by * E + t)) * L + s0;
#pragma unroll
  for (int i = 0; i < 4; ++i) *(uint4*)(dst + i * 8) = *(uint4*)&us[i * 8];
}

// ---------------- K3: Retr = (P_unnorm . V) * isum  via MFMA ------------------------
__global__ __launch_bounds__(256) void k3_retr(const u16* __restrict__ sbh,
                                               const u16* __restrict__ vt,
                                               const float* __restrict__ isum,
                                               float* __restrict__ rb) {
  __shared__ __align__(16) u16 Pt[32][40];
  __shared__ __align__(16) u16 Vt[128][40];
  const int t = threadIdx.x;
  const int blk = blockIdx.x;
  const int lt = blk & 31;
  const int bxy = blk >> 5;                    // ((b*4+x)*4+y)
  const int by = (bxy >> 4) * 4 + (bxy & 3);   // b*4+y (vt batch)
  const int srow = (bxy >> 2) * L;             // (b*4+x)*L (Search batch)
  const int l0 = lt * 32;
  const int lane = t & 63, w = t >> 6;
  const int col = lane & 15, quad = lane >> 4;
  const int lw = w >> 1, eg = w & 1;
  floatx4 vf[4];
#pragma unroll
  for (int i = 0; i < 4; ++i) vf[i] = (floatx4){0.f, 0.f, 0.f, 0.f};
  for (int sc = 0; sc < 32; ++sc) {
    const int s0 = sc * 32;
    __syncthreads();
    {  // stage P tile 32l x 32s
      const int r = t >> 3, c = (t & 7) * 4;
      *(uint2*)&Pt[r][c] = *(const uint2*)(sbh + (size_t)(srow + l0 + r) * L + s0 + c);
    }
    {  // stage V^T tile 128e x 32s
      const int e = t >> 1, half = (t & 1) * 16;
      const u16* src = vt + ((size_t)(by * E + e)) * L + s0 + half;
      *(uint4*)&Vt[e][half] = *(const uint4*)src;
      *(uint4*)&Vt[e][half + 8] = *(const uint4*)(src + 8);
    }
    __syncthreads();
    bf16frag pf = *(const bf16frag*)&Pt[lw * 16 + col][quad * 8];
#pragma unroll
    for (int i = 0; i < 4; ++i) {
      bf16frag rf = *(const bf16frag*)&Vt[(eg * 4 + i) * 16 + col][quad * 8];
      vf[i] = __builtin_amdgcn_mfma_f32_16x16x32_bf16(pf, rf, vf[i], 0, 0, 0);
    }
  }
  float is[4];
#pragma unroll
  for (int r = 0; r < 4; ++r) is[r] = isum[srow + l0 + lw * 16 + quad * 4 + r];
  float* dst = rb + ((size_t)(bxy * L + l0 + lw * 16)) * E + eg * 64;
#pragma unroll
  for (int i = 0; i < 4; ++i)
#pragma unroll
    for (int r = 0; r < 4; ++r)
      dst[(size_t)(quad * 4 + r) * E + i * 16 + col] = vf[i][r] * is[r];
}

// ---------------- K4: kp_bf[bxy,m,f] (bf16) = R.Wk^T + bk ; rt_bf[bxy,e,m] = R^T bf16
__global__ __launch_bounds__(256) void k4_kp(const float* __restrict__ rb,
                                             const float* __restrict__ Wk,
                                             const float* __restrict__ bk,
                                             u16* __restrict__ kp_bf,
                                             u16* __restrict__ rt_bf) {
  __shared__ float Rt[32][132];
  __shared__ float Wt[128][36];
  const int t = threadIdx.x;
  const int blk = blockIdx.x;
  const int lt = blk & 31;
  const int bxy = blk >> 5;
  const int l0 = lt * 32;
#pragma unroll
  for (int i = 0; i < 4; ++i) {
    int f = t + i * 256;
    int r = f >> 5, c4 = f & 31;
    *(float4*)&Rt[r][c4 * 4] = *(const float4*)(rb + ((size_t)(bxy * L + l0 + r)) * E + c4 * 4);
  }
  const int m = t >> 3;
  const int fs = (t & 7) << 2;
  for (int ft = 0; ft < 4; ++ft) {
    __syncthreads();
#pragma unroll
    for (int i = 0; i < 4; ++i) {
      int f = t + i * 256;
      int fj = f >> 5, c4 = f & 31;
      float4 wv = *(const float4*)(Wk + (ft * 32 + fj) * E + c4 * 4);
      Wt[c4 * 4 + 0][fj] = wv.x;
      Wt[c4 * 4 + 1][fj] = wv.y;
      Wt[c4 * 4 + 2][fj] = wv.z;
      Wt[c4 * 4 + 3][fj] = wv.w;
    }
    __syncthreads();
    float a0 = 0.f, a1 = 0.f, a2 = 0.f, a3 = 0.f;
#pragma unroll 16
    for (int e = 0; e < 128; ++e) {
      float rv = Rt[m][e];
      float4 wv = *(float4*)&Wt[e][fs];
      a0 += rv * wv.x; a1 += rv * wv.y; a2 += rv * wv.z; a3 += rv * wv.w;
    }
    int fb = ft * 32 + fs;
    ushort4 o4 = make_ushort4(bfr(a0 + bk[fb]), bfr(a1 + bk[fb + 1]),
                              bfr(a2 + bk[fb + 2]), bfr(a3 + bk[fb + 3]));
    *(ushort4*)(kp_bf + ((size_t)(bxy * L + l0 + m)) * E + fb) = o4;
  }
  // transpose epilogue: rt_bf[bxy][e][l] from the staged R tile
  {
    const int e = t >> 1, half = t & 1;
    u16 us[16];
#pragma unroll
    for (int j = 0; j < 16; ++j) us[j] = bfr(Rt[half * 16 + j][e]);
    u16* dst = rt_bf + ((size_t)(bxy * E + e)) * L + l0 + half * 16;
    *(uint4*)dst = *(uint4*)&us[0];
    *(uint4*)(dst + 8) = *(uint4*)&us[8];
  }
}

// ---------------- K5: fused stage 2 via MFMA bf16 (parts=4) -------------------------
__global__ __launch_bounds__(256) void k5_stage2(const float* __restrict__ qp,
                                                 const u16* __restrict__ kp_bf,
                                                 const u16* __restrict__ rt_bf,
                                                 float* __restrict__ vws) {
  __shared__ __align__(16) u16 qpT[32][136];
  __shared__ __align__(16) u16 kpT[32][136];
  __shared__ __align__(16) u16 rtT[128][40];
  __shared__ __align__(16) u16 pT[4][32][40];
  const int t = threadIdx.x;
  const int blk = blockIdx.x;
  const int part = blk & 3;
  const int lt = (blk >> 2) & 31;
  const int bx = blk >> 7;
  const int b = bx >> 2, x = bx & 3;
  const int l0 = lt * 32;
  const int lane = t & 63;
  const int w = t >> 6;
  const int col = lane & 15;
  const int quad = lane >> 4;
  const int lw = w >> 1;
  const int mt = w & 1;
  const int eg = w & 1;

  {
    const int l = t >> 3, e0 = (t & 7) * 16;
    const float* src = qp + (((size_t)((b * L + l0 + l) * X + x)) * E + e0);
    u16 us[16];
#pragma unroll
    for (int i = 0; i < 4; ++i) {
      float4 v = *(const float4*)(src + i * 4);
      us[i * 4 + 0] = bfr(v.x); us[i * 4 + 1] = bfr(v.y);
      us[i * 4 + 2] = bfr(v.z); us[i * 4 + 3] = bfr(v.w);
    }
    *(uint4*)&qpT[l][e0] = *(uint4*)&us[0];
    *(uint4*)&qpT[l][e0 + 8] = *(uint4*)&us[8];
  }
  __syncthreads();
  bf16frag af[4];
#pragma unroll
  for (int k = 0; k < 4; ++k)
    af[k] = *(const bf16frag*)&qpT[lw * 16 + col][k * 32 + quad * 8];

  floatx4 vf[4];
#pragma unroll
  for (int i = 0; i < 4; ++i) vf[i] = (floatx4){0.f, 0.f, 0.f, 0.f};

  const int mc0 = part * 8;
  for (int mc = mc0; mc < mc0 + 8; ++mc) {
    const int m0 = mc * 32;
    floatx4 sf[4];
#pragma unroll
    for (int y = 0; y < 4; ++y) sf[y] = (floatx4){0.f, 0.f, 0.f, 0.f};
    for (int y = 0; y <= x; ++y) {
      __syncthreads();
      {
        const int m = t >> 3, e0 = (t & 7) * 16;
        const u16* src = kp_bf + (((size_t)(bx * 4 + y) * L + m0 + m)) * E + e0;
        uint4 a0 = *(const uint4*)src;
        uint4 a1 = *(const uint4*)(src + 8);
        *(uint4*)&kpT[m][e0] = a0;
        *(uint4*)&kpT[m][e0 + 8] = a1;
      }
      __syncthreads();
#pragma unroll
      for (int k = 0; k < 4; ++k) {
        bf16frag bfv = *(const bf16frag*)&kpT[mt * 16 + col][k * 32 + quad * 8];
        sf[y] = __builtin_amdgcn_mfma_f32_16x16x32_bf16(af[k], bfv, sf[y], 0, 0, 0);
      }
    }
    u16 pu[4][4];
#pragma unroll
    for (int r = 0; r < 4; ++r) {
      float zz[4];
      float mx = -3.4e38f;
      for (int y = 0; y <= x; ++y) { zz[y] = sf[y][r] * SCALE; mx = fmaxf(mx, zz[y]); }
      float sum = 0.f;
      for (int y = 0; y <= x; ++y) { zz[y] = __expf(zz[y] - mx); sum += zz[y]; }
      float inv = 1.0f / sum;
      for (int y = 0; y <= x; ++y) pu[y][r] = bfr(zz[y] * inv);
    }
    __syncthreads();
#pragma unroll 1
    for (int y = 0; y <= x; ++y)
#pragma unroll
      for (int r = 0; r < 4; ++r)
        pT[y][lw * 16 + quad * 4 + r][mt * 16 + col] = pu[y][r];
    for (int y = 0; y <= x; ++y) {
      __syncthreads();
      {
        const int e = t >> 1, half = t & 1;
        const u16* src = rt_bf + (((size_t)(bx * 4 + y) * E + e)) * L + m0 + half * 16;
        uint4 a0 = *(const uint4*)src;
        uint4 a1 = *(const uint4*)(src + 8);
        *(uint4*)&rtT[e][half * 16] = a0;
        *(uint4*)&rtT[e][half * 16 + 8] = a1;
      }
      __syncthreads();
      bf16frag pf = *(const bf16frag*)&pT[y][lw * 16 + col][quad * 8];
#pragma unroll
      for (int i = 0; i < 4; ++i) {
        const int et = eg * 4 + i;
        bf16frag rf = *(const bf16frag*)&rtT[et * 16 + col][quad * 8];
        vf[i] = __builtin_amdgcn_mfma_f32_16x16x32_bf16(pf, rf, vf[i], 0, 0, 0);
      }
    }
  }
  float* dst = vws + (size_t)part * (B * L * 512) + ((size_t)bx * L + l0) * E;
#pragma unroll
  for (int i = 0; i < 4; ++i)
#pragma unroll
    for (int r = 0; r < 4; ++r)
      dst[((size_t)(lw * 16 + quad * 4 + r)) * E + (eg * 4 + i) * 16 + col] = vf[i][r];
}

// ---------------- K6: sum 4 partials, reorder (x,e)->flat(e*4+x), project with Wv ---
__global__ __launch_bounds__(256) void k6_vout(const float* __restrict__ vws,
                                               const float* __restrict__ Wv,
                                               const float* __restrict__ bv,
                                               float* __restrict__ vout) {
  __shared__ float rowx[4][132];
  const int t = threadIdx.x;
  const int bl = blockIdx.x;
  {
    const int o = t * 2;
    const int xh = o >> 7, e = o & 127;
    const int b = bl >> 10, l = bl & 1023;
    const size_t base = ((size_t)((b * 4 + xh) * 1024 + l)) * 128 + e;
    float sx = 0.f, sy = 0.f;
#pragma unroll
    for (int p = 0; p < 4; ++p) {
      float2 v = *(const float2*)(vws + (size_t)p * 1048576 + base);
      sx += v.x; sy += v.y;
    }
    rowx[xh][e] = sx; rowx[xh][e + 1] = sy;
  }
  __syncthreads();
#pragma unroll
  for (int rep = 0; rep < 2; ++rep) {
    const int o = t + rep * 256;
    const int s = o >> 7, f = o & 127;
    const float4* wr = (const float4*)(Wv + f * E);
    float acc = 0.f;
#pragma unroll 8
    for (int e4 = 0; e4 < 32; ++e4) {
      float4 wv = wr[e4];
      acc += wv.x * rowx[0][s * 32 + e4] + wv.y * rowx[1][s * 32 + e4]
           + wv.z * rowx[2][s * 32 + e4] + wv.w * rowx[3][s * 32 + e4];
    }
    vout[(size_t)bl * 512 + o] = acc + bv[f];
  }
}

// ---------------- K7: Gaussian prior + sig output (f64 sigma chain for accuracy) ----
__global__ __launch_bounds__(256) void k7_prior(const float* __restrict__ sigma,
                                                float* __restrict__ prior,
                                                float* __restrict__ sigout) {
  const int row = blockIdx.x;
  const int bx = row >> 10;
  const int i = row & 1023;
  const int b = bx >> 2, x = bx & 3;
  const double sv = (double)sigma[((size_t)(b * L + i)) * X + x];
  const double sg = 1.0 / (1.0 + exp(-5.0 * sv)) + 1e-5;
  const double s3 = exp(sg * 1.0986122886681098) - 1.0;
  const float coef = (float)(1.0 / (2.5066282746310002 * s3));
  const float inv2s2 = (float)(0.5 / (s3 * s3));
  const int t = threadIdx.x;
  const float di = (float)i;
  const int j0 = t * 4;
  float4 o; float d;
  d = di - (float)(j0 + 0); o.x = coef * expf(-d * d * inv2s2);
  d = di - (float)(j0 + 1); o.y = coef * expf(-d * d * inv2s2);
  d = di - (float)(j0 + 2); o.z = coef * expf(-d * d * inv2s2);
  d = di - (float)(j0 + 3); o.w = coef * expf(-d * d * inv2s2);
  *(float4*)(prior + (size_t)row * 1024 + j0) = o;
  if (t == 0) sigout[row] = (float)s3;
}

extern "C" void kernel_launch(void* const* d_in, const int* in_sizes, int n_in,
                              void* d_out, int out_size, void* d_ws, size_t ws_size,
                              hipStream_t stream) {
  const float* q     = (const float*)d_in[1];
  const float* key   = (const float*)d_in[2];
  const float* value = (const float*)d_in[3];
  const float* sigma = (const float*)d_in[4];
  const float* qp    = (const float*)d_in[8];
  const float* Wk    = (const float*)d_in[9];
  const float* bk    = (const float*)d_in[10];
  const float* Wv    = (const float*)d_in[11];
  const float* bv    = (const float*)d_in[12];

  float* out    = (float*)d_out;
  float* Vout   = out;
  float* sout   = out + 1048576;
  float* prior  = out + 9437184;
  float* sigout = out + 17825792;

  // ws layout (float-unit offsets), peak 10M floats = 40 MB. Lifetimes
  // (launch order k0q,k1,k2v,k3,k4,k5,k6):
  //  sbh  [0, 4M)            u16[8M]  k1 w, k3 r  (bf16 unnorm P)
  //  qkb  [4M, 5M)           u16[2M]  k0q w, k1 r (qb 1M u16, kb 1M u16)
  //  vt   [5.25M, 5.75M)     u16[1M]  k2v w, k3 r
  //  isum [5.75M, 5.75M+8K)  f32      k1 w, k3 r
  //  rb   [6M, 10M)          f32      k3 w, k4 r
  //  kp_bf[4M,4.5M) rt_bf[4.5M,5M)   u16[1M] each, k4 w, k5 r (overlay dead qkb)
  //  vws  [0, 4M)            f32      k5 w, k6 r (overlays dead sbh)
  float* ws    = (float*)d_ws;
  u16*   sbh   = (u16*)ws;
  u16*   qb    = (u16*)(ws + 4194304);
  u16*   kb    = qb + 1048576;
  u16*   vt    = (u16*)(ws + 5242880);
  float* isum  = ws + 6029312;
  float* rb    = ws + 6291456;
  u16*   kp_bf = (u16*)(ws + 4194304);
  u16*   rt_bf = (u16*)(ws + 4718592);
  float* vws   = ws;

  hipLaunchKernelGGL(k0_fill,       dim3(8192), dim3(256), 0, stream, (float4*)sout, 2097152);
  hipLaunchKernelGGL(k0q_convert,   dim3(1024), dim3(256), 0, stream, q, key, (u16*)qb);
  hipLaunchKernelGGL(k1_mfma,       dim3(512),  dim3(512), 0, stream, qb, kb, sbh, isum);
  hipLaunchKernelGGL(k2v_transpose, dim3(256),  dim3(128), 0, stream, value, vt);
  hipLaunchKernelGGL(k3_retr,       dim3(1024), dim3(256), 0, stream, sbh, vt, isum, rb);
  hipLaunchKernelGGL(k4_kp,         dim3(1024), dim3(256), 0, stream, rb, Wk, bk, kp_bf, rt_bf);
  hipLaunchKernelGGL(k5_stage2,     dim3(1024), dim3(256), 0, stream, qp, kp_bf, rt_bf, vws);
  hipLaunchKernelGGL(k6_vout,       dim3(2048), dim3(256), 0, stream, vws, Wv, bv, Vout);
  hipLaunchKernelGGL(k7_prior,      dim3(8192), dim3(256), 0, stream, sigma, prior, sigout);
}

// Round 7
// 374.960 us; speedup vs baseline: 3.1574x; 1.1404x over previous
//
#include <hip/hip_runtime.h>
#include <math.h>

#define B 2
#define L 1024
#define X 4
#define E 128
#define Y 4
#define SCALE 0.08838834764831845f  // 1/sqrt(128)

typedef unsigned short u16;
typedef __attribute__((ext_vector_type(8))) short bf16frag;   // 8 bf16 (4 VGPRs)
typedef __attribute__((ext_vector_type(4))) float floatx4;    // 4 fp32 acc

// round-to-nearest-even f32 -> bf16
static __device__ __forceinline__ u16 bfr(float f) {
  union { float f; unsigned u; } c; c.f = f;
  unsigned r = (c.u + 0x7fffu + ((c.u >> 16) & 1u)) >> 16;
  return (u16)r;
}

// ---------------- K0: series_out is identically 0.25 (mean over the softmax axis) ----
__global__ __launch_bounds__(256) void k0_fill(float4* __restrict__ p, int n4) {
  int i = blockIdx.x * 256 + threadIdx.x;
  if (i < n4) p[i] = make_float4(0.25f, 0.25f, 0.25f, 0.25f);
}

// ---------------- K0q: convert q,key fp32 [b,l,x,e] -> bf16 [bx][l][e] --------------
__global__ __launch_bounds__(256) void k0q_convert(const float* __restrict__ q,
                                                   const float* __restrict__ key,
                                                   u16* __restrict__ qkb) {
  const int f = blockIdx.x * 256 + threadIdx.x;   // 262144 total
  const int row = f >> 4, c8 = (f & 15) * 8;
  const int sel = row >> 13, row2 = row & 8191;   // row2 = b*4096 + l*4 + x
  const int b = row2 >> 12, l = (row2 >> 2) & 1023, x = row2 & 3;
  const float* src = (sel ? key : q) + (size_t)row2 * E + c8;
  float4 v0 = *(const float4*)src;
  float4 v1 = *(const float4*)(src + 4);
  u16 us[8] = {bfr(v0.x), bfr(v0.y), bfr(v0.z), bfr(v0.w),
               bfr(v1.x), bfr(v1.y), bfr(v1.z), bfr(v1.w)};
  u16* dst = qkb + (size_t)(sel * 8192 + (b * 4 + x) * 1024 + l) * E + c8;
  *(uint4*)dst = *(uint4*)us;
}

// ---------------- K1: MFMA QK^T, SINGLE-pass (no max: |score| <= ~6, exp safe) ------
// Writes unnormalized exp(score) bf16 P + isum = 1/rowsum. k34 folds normalization in.
__global__ __launch_bounds__(512) void k1_mfma(const u16* __restrict__ qb,
                                               const u16* __restrict__ kb,
                                               u16* __restrict__ sbh,
                                               float* __restrict__ isum) {
  __shared__ __align__(16) u16 Qt[16][136];
  __shared__ __align__(16) u16 Kt[128][136];
  __shared__ float red[8][16];
  const int t = threadIdx.x;
  const int blk = blockIdx.x;
  const int lt = blk & 63, bx = blk >> 6;
  const int l0 = lt * 16;
  const int lane = t & 63, w = t >> 6;
  const int col = lane & 15, quad = lane >> 4;
  if (t < 256) {
    const int r = t >> 4, c8 = (t & 15) * 8;
    *(uint4*)&Qt[r][c8] = *(const uint4*)(qb + (size_t)(bx * L + l0 + r) * E + c8);
  }
  __syncthreads();
  bf16frag af[4];
#pragma unroll
  for (int k = 0; k < 4; ++k)
    af[k] = *(const bf16frag*)&Qt[col][k * 32 + quad * 8];

  float rs[4] = {0.f, 0.f, 0.f, 0.f};
  for (int sc = 0; sc < 8; ++sc) {
    __syncthreads();
    {
      const int r = t >> 2, c = (t & 3) * 32;
      const u16* src = kb + (size_t)(bx * L + sc * 128 + r) * E + c;
#pragma unroll
      for (int i = 0; i < 4; ++i)
        *(uint4*)&Kt[r][c + i * 8] = *(const uint4*)(src + i * 8);
    }
    __syncthreads();
    floatx4 acc = (floatx4){0.f, 0.f, 0.f, 0.f};
#pragma unroll
    for (int k = 0; k < 4; ++k) {
      bf16frag bk = *(const bf16frag*)&Kt[w * 16 + col][k * 32 + quad * 8];
      acc = __builtin_amdgcn_mfma_f32_16x16x32_bf16(af[k], bk, acc, 0, 0, 0);
    }
    const size_t so = (size_t)sc * 128 + w * 16 + col;
#pragma unroll
    for (int r = 0; r < 4; ++r) {
      float p = __expf(acc[r] * SCALE);
      rs[r] += p;
      sbh[(size_t)(bx * L + l0 + quad * 4 + r) * L + so] = bfr(p);
    }
  }
#pragma unroll
  for (int m = 1; m <= 8; m <<= 1)
#pragma unroll
    for (int r = 0; r < 4; ++r) rs[r] += __shfl_xor(rs[r], m, 64);
  __syncthreads();
  if (col == 0)
#pragma unroll
    for (int r = 0; r < 4; ++r) red[w][quad * 4 + r] = rs[r];
  __syncthreads();
  if (w == 0 && col == 0)
#pragma unroll
    for (int r = 0; r < 4; ++r) {
      float s = 0.f;
#pragma unroll
      for (int j = 0; j < 8; ++j) s += red[j][quad * 4 + r];
      isum[bx * L + l0 + quad * 4 + r] = 1.0f / s;
    }
}

// ---------------- K2v: vt[(b*4+y)*128+e][s] = bf16(value[b,s,y,e]) ------------------
__global__ __launch_bounds__(128) void k2v_transpose(const float* __restrict__ value,
                                                     u16* __restrict__ vt) {
  const int blk = blockIdx.x;       // by*32 + sc
  const int sc = blk & 31, by = blk >> 5;
  const int b = by >> 2, y = by & 3;
  const int t = threadIdx.x;        // e
  const int s0 = sc * 32;
  u16 us[32];
#pragma unroll 8
  for (int ss = 0; ss < 32; ++ss)
    us[ss] = bfr(value[((size_t)((b * L + s0 + ss) * Y + y)) * E + t]);
  u16* dst = vt + ((size_t)(by * E + t)) * L + s0;
#pragma unroll
  for (int i = 0; i < 4; ++i) *(uint4*)(dst + i * 8) = *(uint4*)&us[i * 8];
}

// ---------------- K34: fused Retr (MFMA) + Wk projection (MFMA) + transposes --------
// Phase A (== old k3): R = (P_unnorm . V) * isum into LDS Rt (no global rb).
// Phase B (== old k4): kp_bf = bf16(R.Wk^T + bk), rt_bf = bf16(R^T).
__global__ __launch_bounds__(256) void k34_retr_kp(const u16* __restrict__ sbh,
                                                   const u16* __restrict__ vt,
                                                   const float* __restrict__ isum,
                                                   const float* __restrict__ Wk,
                                                   const float* __restrict__ bk,
                                                   u16* __restrict__ kp_bf,
                                                   u16* __restrict__ rt_bf) {
  __shared__ __align__(16) unsigned char smem[32 * 132 * 4];  // 16.9 KB union
  u16 (*Pt)[40] = (u16(*)[40])smem;                // 32x40 u16 (2.5 KB)
  u16 (*Vt)[40] = (u16(*)[40])(smem + 2560);       // 128x40 u16 (10 KB)
  float (*Rt)[132] = (float(*)[132])smem;          // 32x132 f32, after barrier
  const int t = threadIdx.x;
  const int blk = blockIdx.x;
  const int lt = blk & 31;
  const int bxy = blk >> 5;                    // ((b*4+x)*4+y)
  const int by = (bxy >> 4) * 4 + (bxy & 3);   // b*4+y (vt batch)
  const int srow = (bxy >> 2) * L;             // (b*4+x)*L (Search batch)
  const int l0 = lt * 32;
  const int lane = t & 63, w = t >> 6;
  const int col = lane & 15, quad = lane >> 4;
  const int lw = w >> 1, eg = w & 1;
  floatx4 vf[4];
#pragma unroll
  for (int i = 0; i < 4; ++i) vf[i] = (floatx4){0.f, 0.f, 0.f, 0.f};
  for (int sc = 0; sc < 32; ++sc) {
    const int s0 = sc * 32;
    __syncthreads();
    {  // stage P tile 32l x 32s
      const int r = t >> 3, c = (t & 7) * 4;
      *(uint2*)&Pt[r][c] = *(const uint2*)(sbh + (size_t)(srow + l0 + r) * L + s0 + c);
    }
    {  // stage V^T tile 128e x 32s
      const int e = t >> 1, half = (t & 1) * 16;
      const u16* src = vt + ((size_t)(by * E + e)) * L + s0 + half;
      *(uint4*)&Vt[e][half] = *(const uint4*)src;
      *(uint4*)&Vt[e][half + 8] = *(const uint4*)(src + 8);
    }
    __syncthreads();
    bf16frag pf = *(const bf16frag*)&Pt[lw * 16 + col][quad * 8];
#pragma unroll
    for (int i = 0; i < 4; ++i) {
      bf16frag rf = *(const bf16frag*)&Vt[(eg * 4 + i) * 16 + col][quad * 8];
      vf[i] = __builtin_amdgcn_mfma_f32_16x16x32_bf16(pf, rf, vf[i], 0, 0, 0);
    }
  }
  float is[4];
#pragma unroll
  for (int r = 0; r < 4; ++r) is[r] = isum[srow + l0 + lw * 16 + quad * 4 + r];
  __syncthreads();  // all Pt/Vt reads done; smem becomes Rt
#pragma unroll
  for (int i = 0; i < 4; ++i)
#pragma unroll
    for (int r = 0; r < 4; ++r)
      Rt[lw * 16 + quad * 4 + r][(eg * 4 + i) * 16 + col] = vf[i][r] * is[r];
  __syncthreads();
  // ---- Phase B1: kp = R . Wk^T + bk via MFMA (A from Rt, B direct from global Wk)
  bf16frag aR[4];
#pragma unroll
  for (int k = 0; k < 4; ++k) {
    u16 us[8];
#pragma unroll
    for (int j = 0; j < 8; ++j) us[j] = bfr(Rt[lw * 16 + col][k * 32 + quad * 8 + j]);
    aR[k] = *(bf16frag*)us;
  }
#pragma unroll
  for (int ft = 0; ft < 4; ++ft) {
    const int f0 = (eg * 4 + ft) * 16;
    floatx4 c = (floatx4){0.f, 0.f, 0.f, 0.f};
#pragma unroll
    for (int k = 0; k < 4; ++k) {
      const float* wr = Wk + (size_t)(f0 + col) * E + k * 32 + quad * 8;
      float4 w0 = *(const float4*)wr;
      float4 w1 = *(const float4*)(wr + 4);
      u16 us[8] = {bfr(w0.x), bfr(w0.y), bfr(w0.z), bfr(w0.w),
                   bfr(w1.x), bfr(w1.y), bfr(w1.z), bfr(w1.w)};
      bf16frag bf = *(bf16frag*)us;
      c = __builtin_amdgcn_mfma_f32_16x16x32_bf16(aR[k], bf, c, 0, 0, 0);
    }
    const float bias = bk[f0 + col];
#pragma unroll
    for (int r = 0; r < 4; ++r)
      kp_bf[((size_t)(bxy * L + l0 + lw * 16 + quad * 4 + r)) * E + f0 + col] =
          bfr(c[r] + bias);
  }
  // ---- Phase B2: rt_bf[bxy][e][l] = bf16(R^T) from Rt
  {
    const int e = t >> 1, half = t & 1;
    u16 us[16];
#pragma unroll
    for (int j = 0; j < 16; ++j) us[j] = bfr(Rt[half * 16 + j][e]);
    u16* dst = rt_bf + ((size_t)(bxy * E + e)) * L + l0 + half * 16;
    *(uint4*)dst = *(uint4*)&us[0];
    *(uint4*)(dst + 8) = *(uint4*)&us[8];
  }
}

// ---------------- K5: fused stage 2 via MFMA bf16 (parts=8, no qpT LDS) -------------
__global__ __launch_bounds__(256) void k5_stage2(const float* __restrict__ qp,
                                                 const u16* __restrict__ kp_bf,
                                                 const u16* __restrict__ rt_bf,
                                                 float* __restrict__ vws) {
  __shared__ __align__(16) u16 kpT[32][136];
  __shared__ __align__(16) u16 rtT[128][40];
  __shared__ __align__(16) u16 pT[4][32][40];
  const int t = threadIdx.x;
  const int blk = blockIdx.x;
  const int part = blk & 7;
  const int lt = (blk >> 3) & 31;
  const int bx = blk >> 8;
  const int b = bx >> 2, x = bx & 3;
  const int l0 = lt * 32;
  const int lane = t & 63;
  const int w = t >> 6;
  const int col = lane & 15;
  const int quad = lane >> 4;
  const int lw = w >> 1;
  const int mt = w & 1;
  const int eg = w & 1;

  // A-frags converted directly from global qp (fp32 -> bf16), no LDS round-trip
  bf16frag af[4];
  {
    const float* qpr = qp + ((size_t)((b * L + l0 + lw * 16 + col) * X + x)) * E;
#pragma unroll
    for (int k = 0; k < 4; ++k) {
      float4 v0 = *(const float4*)(qpr + k * 32 + quad * 8);
      float4 v1 = *(const float4*)(qpr + k * 32 + quad * 8 + 4);
      u16 us[8] = {bfr(v0.x), bfr(v0.y), bfr(v0.z), bfr(v0.w),
                   bfr(v1.x), bfr(v1.y), bfr(v1.z), bfr(v1.w)};
      af[k] = *(bf16frag*)us;
    }
  }
  floatx4 vf[4];
#pragma unroll
  for (int i = 0; i < 4; ++i) vf[i] = (floatx4){0.f, 0.f, 0.f, 0.f};

  const int mc0 = part * 4;
  for (int mc = mc0; mc < mc0 + 4; ++mc) {
    const int m0 = mc * 32;
    floatx4 sf[4];
#pragma unroll
    for (int y = 0; y < 4; ++y) sf[y] = (floatx4){0.f, 0.f, 0.f, 0.f};
    for (int y = 0; y <= x; ++y) {
      __syncthreads();
      {
        const int m = t >> 3, e0 = (t & 7) * 16;
        const u16* src = kp_bf + (((size_t)(bx * 4 + y) * L + m0 + m)) * E + e0;
        uint4 a0 = *(const uint4*)src;
        uint4 a1 = *(const uint4*)(src + 8);
        *(uint4*)&kpT[m][e0] = a0;
        *(uint4*)&kpT[m][e0 + 8] = a1;
      }
      __syncthreads();
#pragma unroll
      for (int k = 0; k < 4; ++k) {
        bf16frag bfv = *(const bf16frag*)&kpT[mt * 16 + col][k * 32 + quad * 8];
        sf[y] = __builtin_amdgcn_mfma_f32_16x16x32_bf16(af[k], bfv, sf[y], 0, 0, 0);
      }
    }
    u16 pu[4][4];
#pragma unroll
    for (int r = 0; r < 4; ++r) {
      float zz[4];
      float mx = -3.4e38f;
      for (int y = 0; y <= x; ++y) { zz[y] = sf[y][r] * SCALE; mx = fmaxf(mx, zz[y]); }
      float sum = 0.f;
      for (int y = 0; y <= x; ++y) { zz[y] = __expf(zz[y] - mx); sum += zz[y]; }
      float inv = 1.0f / sum;
      for (int y = 0; y <= x; ++y) pu[y][r] = bfr(zz[y] * inv);
    }
    __syncthreads();  // previous mc's PV reads of pT complete
#pragma unroll 1
    for (int y = 0; y <= x; ++y)
#pragma unroll
      for (int r = 0; r < 4; ++r)
        pT[y][lw * 16 + quad * 4 + r][mt * 16 + col] = pu[y][r];
    for (int y = 0; y <= x; ++y) {
      __syncthreads();
      {
        const int e = t >> 1, half = t & 1;
        const u16* src = rt_bf + (((size_t)(bx * 4 + y) * E + e)) * L + m0 + half * 16;
        uint4 a0 = *(const uint4*)src;
        uint4 a1 = *(const uint4*)(src + 8);
        *(uint4*)&rtT[e][half * 16] = a0;
        *(uint4*)&rtT[e][half * 16 + 8] = a1;
      }
      __syncthreads();
      bf16frag pf = *(const bf16frag*)&pT[y][lw * 16 + col][quad * 8];
#pragma unroll
      for (int i = 0; i < 4; ++i) {
        const int et = eg * 4 + i;
        bf16frag rf = *(const bf16frag*)&rtT[et * 16 + col][quad * 8];
        vf[i] = __builtin_amdgcn_mfma_f32_16x16x32_bf16(pf, rf, vf[i], 0, 0, 0);
      }
    }
  }
  float* dst = vws + (size_t)part * (B * L * 512) + ((size_t)bx * L + l0) * E;
#pragma unroll
  for (int i = 0; i < 4; ++i)
#pragma unroll
    for (int r = 0; r < 4; ++r)
      dst[((size_t)(lw * 16 + quad * 4 + r)) * E + (eg * 4 + i) * 16 + col] = vf[i][r];
}

// ---------------- K6: sum 8 partials, reorder (x,e)->flat(e*4+x), project with Wv ---
__global__ __launch_bounds__(256) void k6_vout(const float* __restrict__ vws,
                                               const float* __restrict__ Wv,
                                               const float* __restrict__ bv,
                                               float* __restrict__ vout) {
  __shared__ float rowx[4][132];
  const int t = threadIdx.x;
  const int bl = blockIdx.x;
  {
    const int o = t * 2;
    const int xh = o >> 7, e = o & 127;
    const int b = bl >> 10, l = bl & 1023;
    const size_t base = ((size_t)((b * 4 + xh) * 1024 + l)) * 128 + e;
    float sx = 0.f, sy = 0.f;
#pragma unroll
    for (int p = 0; p < 8; ++p) {
      float2 v = *(const float2*)(vws + (size_t)p * 1048576 + base);
      sx += v.x; sy += v.y;
    }
    rowx[xh][e] = sx; rowx[xh][e + 1] = sy;
  }
  __syncthreads();
#pragma unroll
  for (int rep = 0; rep < 2; ++rep) {
    const int o = t + rep * 256;
    const int s = o >> 7, f = o & 127;
    const float4* wr = (const float4*)(Wv + f * E);
    float acc = 0.f;
#pragma unroll 8
    for (int e4 = 0; e4 < 32; ++e4) {
      float4 wv = wr[e4];
      acc += wv.x * rowx[0][s * 32 + e4] + wv.y * rowx[1][s * 32 + e4]
           + wv.z * rowx[2][s * 32 + e4] + wv.w * rowx[3][s * 32 + e4];
    }
    vout[(size_t)bl * 512 + o] = acc + bv[f];
  }
}

// ---------------- K7: Gaussian prior + sig output (f64 sigma chain for accuracy) ----
__global__ __launch_bounds__(256) void k7_prior(const float* __restrict__ sigma,
                                                float* __restrict__ prior,
                                                float* __restrict__ sigout) {
  const int row = blockIdx.x;
  const int bx = row >> 10;
  const int i = row & 1023;
  const int b = bx >> 2, x = bx & 3;
  const double sv = (double)sigma[((size_t)(b * L + i)) * X + x];
  const double sg = 1.0 / (1.0 + exp(-5.0 * sv)) + 1e-5;
  const double s3 = exp(sg * 1.0986122886681098) - 1.0;
  const float coef = (float)(1.0 / (2.5066282746310002 * s3));
  const float inv2s2 = (float)(0.5 / (s3 * s3));
  const int t = threadIdx.x;
  const float di = (float)i;
  const int j0 = t * 4;
  float4 o; float d;
  d = di - (float)(j0 + 0); o.x = coef * expf(-d * d * inv2s2);
  d = di - (float)(j0 + 1); o.y = coef * expf(-d * d * inv2s2);
  d = di - (float)(j0 + 2); o.z = coef * expf(-d * d * inv2s2);
  d = di - (float)(j0 + 3); o.w = coef * expf(-d * d * inv2s2);
  *(float4*)(prior + (size_t)row * 1024 + j0) = o;
  if (t == 0) sigout[row] = (float)s3;
}

extern "C" void kernel_launch(void* const* d_in, const int* in_sizes, int n_in,
                              void* d_out, int out_size, void* d_ws, size_t ws_size,
                              hipStream_t stream) {
  const float* q     = (const float*)d_in[1];
  const float* key   = (const float*)d_in[2];
  const float* value = (const float*)d_in[3];
  const float* sigma = (const float*)d_in[4];
  const float* qp    = (const float*)d_in[8];
  const float* Wk    = (const float*)d_in[9];
  const float* bk    = (const float*)d_in[10];
  const float* Wv    = (const float*)d_in[11];
  const float* bv    = (const float*)d_in[12];

  float* out    = (float*)d_out;
  float* Vout   = out;
  float* sout   = out + 1048576;
  float* prior  = out + 9437184;
  float* sigout = out + 17825792;

  // ws layout (float-unit offsets), peak 9,437,184 floats = 37.7 MB. Lifetimes
  // (launch order k0q,k1,k2v,k34,k5,k6):
  //  sbh  [0, 4M)            u16[8M]  k1 w, k34 r  (bf16 unnorm P)
  //  qkb  [4M, 5M)           u16[2M]  k0q w, k1 r  (qb 1M u16, kb 1M u16)
  //  vt   [5M, 5.5M)         u16[1M]  k2v w, k34 r
  //  isum [5.5M, 5.5M+8K)    f32      k1 w, k34 r
  //  kp_bf[8M, 8.5M) rt_bf[8.5M, 9M) u16[1M] each, k34 w, k5 r
  //  vws  [0, 8M)            f32      k5 w, k6 r  (overlays sbh/qkb/vt/isum, all
  //                                   dead after k34; disjoint from kp/rt)
  float* ws    = (float*)d_ws;
  u16*   sbh   = (u16*)ws;
  u16*   qb    = (u16*)(ws + 4194304);
  u16*   kb    = qb + 1048576;
  u16*   vt    = (u16*)(ws + 5242880);
  float* isum  = ws + 5767168;
  u16*   kp_bf = (u16*)(ws + 8388608);
  u16*   rt_bf = (u16*)(ws + 8912896);
  float* vws   = ws;

  hipLaunchKernelGGL(k0_fill,       dim3(8192), dim3(256), 0, stream, (float4*)sout, 2097152);
  hipLaunchKernelGGL(k0q_convert,   dim3(1024), dim3(256), 0, stream, q, key, (u16*)qb);
  hipLaunchKernelGGL(k1_mfma,       dim3(512),  dim3(512), 0, stream, qb, kb, sbh, isum);
  hipLaunchKernelGGL(k2v_transpose, dim3(256),  dim3(128), 0, stream, value, vt);
  hipLaunchKernelGGL(k34_retr_kp,   dim3(1024), dim3(256), 0, stream, sbh, vt, isum, Wk, bk, kp_bf, rt_bf);
  hipLaunchKernelGGL(k5_stage2,     dim3(2048), dim3(256), 0, stream, qp, kp_bf, rt_bf, vws);
  hipLaunchKernelGGL(k6_vout,       dim3(2048), dim3(256), 0, stream, vws, Wv, bv, Vout);
  hipLaunchKernelGGL(k7_prior,      dim3(8192), dim3(256), 0, stream, sigma, prior, sigout);
}